// Round 12
// baseline (1080.422 us; speedup 1.0000x reference)
//
#include <hip/hip_runtime.h>
#include <hip/hip_bf16.h>

#define NN 20000
#define NE 60000
#define NT 1024

typedef unsigned short ushortT;
typedef __attribute__((ext_vector_type(8))) short bf16x8;
typedef __attribute__((ext_vector_type(8))) unsigned short u16x8;
typedef __attribute__((ext_vector_type(4))) float f32x4;

__device__ __forceinline__ float sigm(float x){ return 1.0f/(1.0f+expf(-x)); }
__device__ __forceinline__ float bfu2f(ushortT u){ return __uint_as_float(((unsigned)u)<<16); }
__device__ __forceinline__ ushortT f2bfu(float f){
  __hip_bfloat16 b = __float2bfloat16(f);
  return *reinterpret_cast<ushortT*>(&b);
}

// ---------------- lin0: out = relu(x @ W0.T + b0); h = out ----------------
__global__ void k_lin0(const float* __restrict__ x, const float* __restrict__ W0,
                       const float* __restrict__ b0, float* __restrict__ out,
                       float* __restrict__ h, ushortT* __restrict__ outbf,
                       ushortT* __restrict__ hbf){
  int idx = blockIdx.x*256 + threadIdx.x;       // N*64 exact
  int n = idx >> 6, j = idx & 63;
  float a = b0[j] + x[n*3+0]*W0[j*3+0] + x[n*3+1]*W0[j*3+1] + x[n*3+2]*W0[j*3+2];
  a = fmaxf(a, 0.0f);
  out[idx] = a; h[idx] = a;
  ushortT u = f2bfu(a);
  outbf[idx] = u; hbf[idx] = u;
}

__global__ void k_deg(const int* __restrict__ dst, float* __restrict__ deg){
  int e = blockIdx.x*256 + threadIdx.x;
  if (e < NE) atomicAdd(&deg[dst[e]], 1.0f);
}

// ------------- edge MLP hidden: R = relu(edge_attr @ We1.T + be1) (bf16) ----
__global__ void k_edgemlp(const float* __restrict__ ea, const float* __restrict__ We1,
                          const float* __restrict__ be1, ushortT* __restrict__ Rbf){
  int idx = blockIdx.x*256 + threadIdx.x;       // E*128 exact
  int e = idx >> 7, k = idx & 127;
  float a = be1[k];
  #pragma unroll
  for (int j = 0; j < 7; ++j) a += ea[e*7+j]*We1[k*7+j];
  Rbf[idx] = f2bfu(fmaxf(a, 0.0f));
}

// ------------- fused weight prep: bf16 cvts + rootT transpose -------------
#define PREP_T ((4096*128) + (1536*384) + (128*384) + (192*64) + (192*64) + (64*64))
__global__ void k_prep(const float* __restrict__ We2, const float* __restrict__ memwi,
                       const float* __restrict__ W1, const float* __restrict__ gwih,
                       const float* __restrict__ gwhh, const float* __restrict__ root,
                       ushortT* __restrict__ We2bf, ushortT* __restrict__ wmem,
                       ushortT* __restrict__ w1bf, ushortT* __restrict__ gwihbf,
                       ushortT* __restrict__ gwhhbf, ushortT* __restrict__ rootTbf){
  int idx = blockIdx.x*256 + threadIdx.x;
  if (idx < 4096*128){ We2bf[idx] = f2bfu(We2[idx]); return; }
  idx -= 4096*128;
  if (idx < 1536*384){ wmem[idx] = f2bfu(memwi[idx]); return; }
  idx -= 1536*384;
  if (idx < 128*384){ w1bf[idx] = f2bfu(W1[idx]); return; }
  idx -= 128*384;
  if (idx < 192*64){ gwihbf[idx] = f2bfu(gwih[idx]); return; }
  idx -= 192*64;
  if (idx < 192*64){ gwhhbf[idx] = f2bfu(gwhh[idx]); return; }
  idx -= 192*64;
  if (idx < 64*64){ int d = idx >> 6, j = idx & 63; rootTbf[j*64 + d] = f2bfu(root[idx]); }
}

// ---------- fused NNConv message: agg[dst[e]] += out[src[e]] @ (R[e]@We2^T + be2) ----------
// Grid (235, 2). Barrier-free main loop: B-fragments are loaded per-wave from
// L2-resident We2bf straight into registers, software-pipelined one d-step ahead
// (2-deep register buffer, manually 2x-unrolled so no swap movs). The only
// __syncthreads is the prologue (o_sT/be2q/dst_s). LDS ~43KB.
#define EB 256
__global__ __launch_bounds__(256, 2) void k_fmsg(
    const ushortT* __restrict__ Rbf, const ushortT* __restrict__ We2bf,
    const float* __restrict__ be2, const ushortT* __restrict__ outbf,
    const int* __restrict__ src, const int* __restrict__ dst,
    float* __restrict__ agg)
{
  __shared__ ushortT o_sT[64][264];    // bf16 out[src[e]] transposed [d][edge]
  __shared__ float   be2q[64][32];     // be2 slice for this fh
  __shared__ int     dst_s[EB];

  int tid = threadIdx.x;
  int e0 = blockIdx.x * EB;
  int fh = blockIdx.y;                 // 0..1
  int w = tid >> 6, lane = tid & 63;
  int l15 = lane & 15, g = lane >> 4;  // g in 0..3

  // ---- prologue: dst + o gather (bf16, transposed), be2 slice ----
  {
    int ge = e0 + tid;
    int sn = src[ge];                  // ge < 60160 < 2*NE: stays inside eidx alloc
    dst_s[tid] = (ge < NE) ? dst[ge] : -1;
    const ushortT* op = outbf + (size_t)sn*64;
    #pragma unroll
    for (int i = 0; i < 8; ++i){
      u16x8 v = *reinterpret_cast<const u16x8*>(op + i*8);
      #pragma unroll
      for (int j = 0; j < 8; ++j) o_sT[i*8+j][tid] = v[j];
    }
  }
  #pragma unroll
  for (int i = 0; i < 8; ++i){
    int idx = tid*8 + i;
    int dd = idx >> 5, cc = idx & 31;
    be2q[dd][cc] = be2[(dd<<6) + (fh<<5) + cc];
  }

  // A fragments: R rows for this wave's 64 edges, all K=128 (4 k-steps)
  bf16x8 af[4][4];
  #pragma unroll
  for (int t = 0; t < 4; ++t){
    #pragma unroll
    for (int ks = 0; ks < 4; ++ks){
      int ge = e0 + w*64 + t*16 + l15;
      bf16x8 z = {0,0,0,0,0,0,0,0};
      af[t][ks] = (ge < NE) ? *reinterpret_cast<const bf16x8*>(Rbf + (size_t)ge*128 + ks*32 + g*8) : z;
    }
  }

  f32x4 msg[4][2];
  #pragma unroll
  for (int t = 0; t < 4; ++t){
    #pragma unroll
    for (int q = 0; q < 2; ++q){ msg[t][q][0]=0.f; msg[t][q][1]=0.f; msg[t][q][2]=0.f; msg[t][q][3]=0.f; }
  }
  __syncthreads();   // o_sT / be2q / dst_s visible

  // per-lane B pointers: row c = d*64 + fh*32 + {0,16} + l15, k-offset g*8 + ks*32
  const ushortT* bp0 = We2bf + (size_t)((fh<<5) + l15)*128 + g*8;        // half 0
  const ushortT* bp1 = We2bf + (size_t)((fh<<5) + 16 + l15)*128 + g*8;   // half 1
  const int DSTRIDE = 64*128;          // ushorts per d-step

  bf16x8 bA[8], bB[8];
  auto loadB = [&](const ushortT* p0, const ushortT* p1, bf16x8* bb){
    #pragma unroll
    for (int ks = 0; ks < 4; ++ks){
      bb[ks]     = *reinterpret_cast<const bf16x8*>(p0 + ks*32);
      bb[4 + ks] = *reinterpret_cast<const bf16x8*>(p1 + ks*32);
    }
  };

  auto domfma = [&](int d, const bf16x8* bb){
    f32x4 ac[4][2];
    #pragma unroll
    for (int t = 0; t < 4; ++t){
      #pragma unroll
      for (int q = 0; q < 2; ++q){ ac[t][q][0]=0.f; ac[t][q][1]=0.f; ac[t][q][2]=0.f; ac[t][q][3]=0.f; }
    }
    __builtin_amdgcn_s_setprio(1);
    #pragma unroll
    for (int ks = 0; ks < 4; ++ks){
      #pragma unroll
      for (int t = 0; t < 4; ++t){
        ac[t][0] = __builtin_amdgcn_mfma_f32_16x16x32_bf16(af[t][ks], bb[ks],     ac[t][0], 0, 0, 0);
        ac[t][1] = __builtin_amdgcn_mfma_f32_16x16x32_bf16(af[t][ks], bb[4 + ks], ac[t][1], 0, 0, 0);
      }
    }
    __builtin_amdgcn_s_setprio(0);
    float be2v0 = be2q[d][l15];
    float be2v1 = be2q[d][16 + l15];
    #pragma unroll
    for (int t = 0; t < 4; ++t){
      ushort4 ou = *reinterpret_cast<const ushort4*>(&o_sT[d][w*64 + t*16 + g*4]);
      float o0 = bfu2f(ou.x), o1 = bfu2f(ou.y), o2 = bfu2f(ou.z), o3 = bfu2f(ou.w);
      msg[t][0][0] += o0*(ac[t][0][0] + be2v0);
      msg[t][0][1] += o1*(ac[t][0][1] + be2v0);
      msg[t][0][2] += o2*(ac[t][0][2] + be2v0);
      msg[t][0][3] += o3*(ac[t][0][3] + be2v0);
      msg[t][1][0] += o0*(ac[t][1][0] + be2v1);
      msg[t][1][1] += o1*(ac[t][1][1] + be2v1);
      msg[t][1][2] += o2*(ac[t][1][2] + be2v1);
      msg[t][1][3] += o3*(ac[t][1][3] + be2v1);
    }
  };

  // software pipeline, prefetch distance 1, manually 2x-unrolled (no reg swaps)
  loadB(bp0, bp1, bA); bp0 += DSTRIDE; bp1 += DSTRIDE;          // frags(0)
  for (int d = 0; d < 62; d += 2){
    loadB(bp0, bp1, bB); bp0 += DSTRIDE; bp1 += DSTRIDE;        // frags(d+1)
    domfma(d, bA);
    loadB(bp0, bp1, bA); bp0 += DSTRIDE; bp1 += DSTRIDE;        // frags(d+2)
    domfma(d + 1, bB);
  }
  loadB(bp0, bp1, bB);                                           // frags(63)
  domfma(62, bA);
  domfma(63, bB);

  #pragma unroll
  for (int t = 0; t < 4; ++t){
    #pragma unroll
    for (int r = 0; r < 4; ++r){
      int el = w*64 + t*16 + g*4 + r;
      int tn = dst_s[el];
      if (tn >= 0){
        atomicAdd(&agg[(size_t)tn*64 + (fh<<5) + l15],      msg[t][0][r]);
        atomicAdd(&agg[(size_t)tn*64 + (fh<<5) + 16 + l15], msg[t][1][r]);
      }
    }
  }
}

// ------------- NNConv epilogue + GRU cell via MFMA (32 nodes/block, grid 625) -------------
__global__ __launch_bounds__(256) void k_gru2(
    const float* __restrict__ agg_in, const float* __restrict__ deg,
    const ushortT* __restrict__ rootT, const float* __restrict__ conv_b,
    const ushortT* __restrict__ wih, const ushortT* __restrict__ whh,
    const float* __restrict__ bih, const float* __restrict__ bhh,
    float* __restrict__ out, float* __restrict__ h,
    ushortT* __restrict__ outbf, ushortT* __restrict__ hbf)
{
  __shared__ ushortT mbf[32*64];
  float* agg = const_cast<float*>(agg_in);
  int tid = threadIdx.x;
  int w = tid >> 6, lane = tid & 63;
  int l15 = lane & 15, g = lane >> 4;
  int n0 = blockIdx.x * 32;
  int j = w*16 + l15;

  // ---- stage 1: root transform ----
  f32x4 acc1[2];
  #pragma unroll
  for (int rt = 0; rt < 2; ++rt){ acc1[rt][0]=0.f; acc1[rt][1]=0.f; acc1[rt][2]=0.f; acc1[rt][3]=0.f; }
  bf16x8 ah[2][2];
  #pragma unroll
  for (int ks = 0; ks < 2; ++ks){
    bf16x8 b = *reinterpret_cast<const bf16x8*>(rootT + (size_t)j*64 + g*8 + ks*32);
    #pragma unroll
    for (int rt = 0; rt < 2; ++rt){
      bf16x8 a = *reinterpret_cast<const bf16x8*>(outbf + (size_t)(n0 + rt*16 + l15)*64 + g*8 + ks*32);
      acc1[rt] = __builtin_amdgcn_mfma_f32_16x16x32_bf16(a, b, acc1[rt], 0, 0, 0);
      ah[rt][ks] = *reinterpret_cast<const bf16x8*>(hbf + (size_t)(n0 + rt*16 + l15)*64 + g*8 + ks*32);
    }
  }
  {
    float cb = conv_b[j];
    #pragma unroll
    for (int rt = 0; rt < 2; ++rt){
      #pragma unroll
      for (int r = 0; r < 4; ++r){
        int row = rt*16 + g*4 + r;
        int node = n0 + row;
        float inv = 1.0f/fmaxf(deg[node], 1.0f);
        float mval = fmaxf(acc1[rt][r] + agg[(size_t)node*64 + j]*inv + cb, 0.0f);
        agg[(size_t)node*64 + j] = 0.0f;
        int gran = (j >> 3) ^ (row & 7);
        mbf[row*64 + (gran<<3) + (j & 7)] = f2bfu(mval);
      }
    }
  }
  __syncthreads();   // mbf visible; outbf/hbf reads drained

  // ---- stage 2: gates ----
  f32x4 gx[3][2], gh[3][2];
  #pragma unroll
  for (int ci = 0; ci < 3; ++ci){
    #pragma unroll
    for (int rt = 0; rt < 2; ++rt){
      gx[ci][rt][0]=0.f; gx[ci][rt][1]=0.f; gx[ci][rt][2]=0.f; gx[ci][rt][3]=0.f;
      gh[ci][rt][0]=0.f; gh[ci][rt][1]=0.f; gh[ci][rt][2]=0.f; gh[ci][rt][3]=0.f;
    }
  }
  #pragma unroll
  for (int ks = 0; ks < 2; ++ks){
    bf16x8 am[2];
    #pragma unroll
    for (int rt = 0; rt < 2; ++rt){
      int arow = rt*16 + l15;
      int agran = (g + ks*4) ^ (l15 & 7);
      am[rt] = *reinterpret_cast<const bf16x8*>(&mbf[arow*64 + (agran<<3)]);
    }
    #pragma unroll
    for (int ci = 0; ci < 3; ++ci){
      int c = (w + ci*4)*16 + l15;     // abs gate column (ci = gate)
      bf16x8 bx = *reinterpret_cast<const bf16x8*>(wih + (size_t)c*64 + g*8 + ks*32);
      bf16x8 bh = *reinterpret_cast<const bf16x8*>(whh + (size_t)c*64 + g*8 + ks*32);
      #pragma unroll
      for (int rt = 0; rt < 2; ++rt){
        gx[ci][rt] = __builtin_amdgcn_mfma_f32_16x16x32_bf16(am[rt], bx, gx[ci][rt], 0, 0, 0);
        gh[ci][rt] = __builtin_amdgcn_mfma_f32_16x16x32_bf16(ah[rt][ks], bh, gh[ci][rt], 0, 0, 0);
      }
    }
  }
  // ---- epilogue: GRU update, fully in-register ----
  float bxr = bih[j], bxz = bih[64+j], bxn = bih[128+j];
  float bhr = bhh[j], bhz = bhh[64+j], bhn = bhh[128+j];
  #pragma unroll
  for (int rt = 0; rt < 2; ++rt){
    #pragma unroll
    for (int r = 0; r < 4; ++r){
      int node = n0 + rt*16 + g*4 + r;
      float gxr = gx[0][rt][r] + bxr, gxz = gx[1][rt][r] + bxz, gxn = gx[2][rt][r] + bxn;
      float ghr = gh[0][rt][r] + bhr, ghz = gh[1][rt][r] + bhz, ghn = gh[2][rt][r] + bhn;
      float rr = sigm(gxr + ghr), zz = sigm(gxz + ghz);
      float nn_ = tanhf(gxn + rr*ghn);
      float hold = h[(size_t)node*64 + j];
      float hn = (1.0f - zz)*nn_ + zz*hold;
      h[(size_t)node*64 + j]   = hn;
      out[(size_t)node*64 + j] = hn;
      ushortT u = f2bfu(hn);
      outbf[(size_t)node*64 + j] = u;
      hbf[(size_t)node*64 + j]   = u;
    }
  }
}

// ------------- Set2Set: fused LSTM cell + attention, 7-slot state pipeline -------------
__global__ void k_s2s2(const float* __restrict__ out, const float* __restrict__ wi,
                       const float* __restrict__ wh, const float* __restrict__ bi,
                       const float* __restrict__ bh, float* __restrict__ st, int it){
  const float* sr = st + it*256;
  float* sw = st + (it+1)*256;
  __shared__ float qs[128], hsl[64], gg[256];
  __shared__ float ob[128*65], wl[128], zred[128], part[256];
  int tid = threadIdx.x;      // 256
  int n0 = blockIdx.x * 128;

  // ---- cell (computed redundantly by every block) ----
  if (tid < 64) qs[tid] = sr[tid];
  else if (tid < 128){
    float Z = sr[192];
    qs[tid] = (Z != 0.0f) ? sr[128 + (tid-64)]/Z : 0.0f;
  }
  __syncthreads();
  {
    float a = bi[tid] + bh[tid];
    #pragma unroll 8
    for (int k = 0; k < 128; ++k) a += qs[k]*wi[tid*128 + k];
    #pragma unroll 8
    for (int k = 0; k < 64;  ++k) a += sr[k]*wh[tid*64 + k];
    gg[tid] = a;
  }
  __syncthreads();
  if (tid < 64){
    float iv = sigm(gg[tid]), fv = sigm(gg[64+tid]);
    float gv = tanhf(gg[128+tid]), ov = sigm(gg[192+tid]);
    float c = fv*sr[64+tid] + iv*gv;
    float hnew = ov*tanhf(c);
    hsl[tid] = hnew;
    if (blockIdx.x == 0){ sw[64+tid] = c; sw[tid] = hnew; }
  }
  // ---- attention over this block's 128 nodes ----
  #pragma unroll
  for (int rr = 0; rr < 8; ++rr){
    int idx = rr*1024 + tid*4;
    int nl = idx >> 6, jj = idx & 63;
    float4 v = make_float4(0.f,0.f,0.f,0.f);
    if (n0 + nl < NN) v = *reinterpret_cast<const float4*>(&out[(size_t)(n0+nl)*64 + jj]);
    ob[nl*65 + jj + 0] = v.x; ob[nl*65 + jj + 1] = v.y;
    ob[nl*65 + jj + 2] = v.z; ob[nl*65 + jj + 3] = v.w;
  }
  __syncthreads();
  if (tid < 128){
    float e = 0.f;
    #pragma unroll 8
    for (int jj = 0; jj < 64; ++jj) e += ob[tid*65 + jj]*hsl[jj];
    float wv = (n0 + tid < NN) ? expf(e) : 0.f;
    wl[tid] = wv; zred[tid] = wv;
  }
  __syncthreads();
  if (tid < 64) zred[tid] += zred[tid + 64];
  __syncthreads();
  if (tid < 32) zred[tid] += zred[tid + 32];
  __syncthreads();
  if (tid < 16) zred[tid] += zred[tid + 16];
  __syncthreads();
  if (tid < 8) zred[tid] += zred[tid + 8];
  __syncthreads();
  if (tid == 0){
    float z = zred[0]+zred[1]+zred[2]+zred[3]+zred[4]+zred[5]+zred[6]+zred[7];
    atomicAdd(&sw[192], z);
  }
  {
    int gq = tid >> 6, d = tid & 63;
    float acc = 0.f;
    #pragma unroll 8
    for (int i = 0; i < 32; ++i){
      int nl = gq*32 + i;
      acc += wl[nl]*ob[nl*65 + d];
    }
    part[tid] = acc;
  }
  __syncthreads();
  if (tid < 64)
    atomicAdd(&sw[128 + tid], part[tid] + part[64+tid] + part[128+tid] + part[192+tid]);
}

// ------------- head -------------
__global__ void k_z(const float* __restrict__ out, const float* __restrict__ st,
                    const int* __restrict__ nonring, ushortT* __restrict__ zbf){
  const float* s6 = st + 6*256;
  int idx = blockIdx.x*256 + threadIdx.x;         // T*384 exact
  int t = idx / 384, c = idx % 384;
  float v;
  if (c < 256){
    int a = c*16 + (t >> 6);
    int node = nonring[a];
    v = out[(size_t)node*64 + (t & 63)];
  } else {
    int pi = t >> 3;                              // pool index (quirky repeat)
    v = (pi < 64) ? s6[pi] : s6[128 + (pi - 64)] / s6[192];
  }
  zbf[idx] = f2bfu(v);
}

// memory LSTM via MFMA: gates = zbf @ wmem^T (+biases); hm = sig(o)*tanh(sig(i)*tanh(g))
__global__ __launch_bounds__(256) void k_mem2(
    const ushortT* __restrict__ zbf, const ushortT* __restrict__ wmem,
    const float* __restrict__ membi, const float* __restrict__ membh,
    ushortT* __restrict__ hmbf){
  int tid = threadIdx.x;
  int w = tid >> 6, lane = tid & 63;
  int l15 = lane & 15, g = lane >> 4;
  int m0 = blockIdx.x * 32;
  int jw = blockIdx.y * 64 + w * 16;

  f32x4 ai[2], ag[2], ao[2];
  #pragma unroll
  for (int m = 0; m < 2; ++m){
    #pragma unroll
    for (int r = 0; r < 4; ++r){ ai[m][r]=0.f; ag[m][r]=0.f; ao[m][r]=0.f; }
  }
  const ushortT* a0p = zbf + (size_t)(m0 + l15)*384 + g*8;
  const ushortT* a1p = zbf + (size_t)(m0 + 16 + l15)*384 + g*8;
  const ushortT* bip = wmem + (size_t)(jw + l15)*384 + g*8;
  const ushortT* bgp = wmem + (size_t)(768 + jw + l15)*384 + g*8;
  const ushortT* bop = wmem + (size_t)(1152 + jw + l15)*384 + g*8;
  #pragma unroll
  for (int ks = 0; ks < 12; ++ks){
    bf16x8 a0 = *reinterpret_cast<const bf16x8*>(a0p + ks*32);
    bf16x8 a1 = *reinterpret_cast<const bf16x8*>(a1p + ks*32);
    bf16x8 bi = *reinterpret_cast<const bf16x8*>(bip + ks*32);
    bf16x8 bg = *reinterpret_cast<const bf16x8*>(bgp + ks*32);
    bf16x8 bo = *reinterpret_cast<const bf16x8*>(bop + ks*32);
    ai[0] = __builtin_amdgcn_mfma_f32_16x16x32_bf16(a0, bi, ai[0], 0, 0, 0);
    ai[1] = __builtin_amdgcn_mfma_f32_16x16x32_bf16(a1, bi, ai[1], 0, 0, 0);
    ag[0] = __builtin_amdgcn_mfma_f32_16x16x32_bf16(a0, bg, ag[0], 0, 0, 0);
    ag[1] = __builtin_amdgcn_mfma_f32_16x16x32_bf16(a1, bg, ag[1], 0, 0, 0);
    ao[0] = __builtin_amdgcn_mfma_f32_16x16x32_bf16(a0, bo, ao[0], 0, 0, 0);
    ao[1] = __builtin_amdgcn_mfma_f32_16x16x32_bf16(a1, bo, ao[1], 0, 0, 0);
  }
  int j = jw + l15;
  float bI = membi[j]        + membh[j];
  float bG = membi[768 + j]  + membh[768 + j];
  float bO = membi[1152 + j] + membh[1152 + j];
  #pragma unroll
  for (int m = 0; m < 2; ++m){
    #pragma unroll
    for (int r = 0; r < 4; ++r){
      int t = m0 + m*16 + g*4 + r;
      float gi = ai[m][r] + bI;
      float gG = ag[m][r] + bG;
      float go = ao[m][r] + bO;
      float cm = sigm(gi)*tanhf(gG);
      hmbf[(size_t)t*384 + j] = f2bfu(sigm(go)*tanhf(cm));
    }
  }
}

// fin stage 1 via MFMA: hid = relu(hm @ W1^T + b1)  [1024 x 128] f32
__global__ __launch_bounds__(256) void k_fin1(
    const ushortT* __restrict__ hmbf, const ushortT* __restrict__ w1bf,
    const float* __restrict__ b1, float* __restrict__ hid){
  int tid = threadIdx.x;
  int w = tid >> 6, lane = tid & 63;
  int l15 = lane & 15, g = lane >> 4;
  int m0 = blockIdx.x * 32;
  int cw = blockIdx.y * 64 + w * 16;

  f32x4 acc[2];
  #pragma unroll
  for (int m = 0; m < 2; ++m){
    #pragma unroll
    for (int r = 0; r < 4; ++r) acc[m][r] = 0.f;
  }
  const ushortT* a0p = hmbf + (size_t)(m0 + l15)*384 + g*8;
  const ushortT* a1p = hmbf + (size_t)(m0 + 16 + l15)*384 + g*8;
  const ushortT* bp  = w1bf + (size_t)(cw + l15)*384 + g*8;
  #pragma unroll
  for (int ks = 0; ks < 12; ++ks){
    bf16x8 a0 = *reinterpret_cast<const bf16x8*>(a0p + ks*32);
    bf16x8 a1 = *reinterpret_cast<const bf16x8*>(a1p + ks*32);
    bf16x8 b  = *reinterpret_cast<const bf16x8*>(bp + ks*32);
    acc[0] = __builtin_amdgcn_mfma_f32_16x16x32_bf16(a0, b, acc[0], 0, 0, 0);
    acc[1] = __builtin_amdgcn_mfma_f32_16x16x32_bf16(a1, b, acc[1], 0, 0, 0);
  }
  int c = cw + l15;
  float bv = b1[c];
  #pragma unroll
  for (int m = 0; m < 2; ++m){
    #pragma unroll
    for (int r = 0; r < 4; ++r){
      int t = m0 + m*16 + g*4 + r;
      hid[(size_t)t*128 + c] = fmaxf(acc[m][r] + bv, 0.0f);
    }
  }
}

// fin stage 2: y[t][j] = b2[j] + hid[t] . W2[j]   (j < 6)
__global__ void k_fin2(const float* __restrict__ hid, const float* __restrict__ W2,
                       const float* __restrict__ b2, float* __restrict__ y){
  int tid = threadIdx.x;                 // 256
  int t = blockIdx.x*32 + (tid >> 3);    // grid 32 exact
  int j = tid & 7;
  if (j >= 6) return;
  float a = b2[j];
  const float* hp = hid + (size_t)t*128;
  const float* wp = W2 + j*128;
  #pragma unroll 8
  for (int k = 0; k < 128; ++k) a += hp[k]*wp[k];
  y[t*6 + j] = a;
}

extern "C" void kernel_launch(void* const* d_in, const int* in_sizes, int n_in,
                              void* d_out, int out_size, void* d_ws, size_t ws_size,
                              hipStream_t stream){
  const float* x      = (const float*)d_in[0];
  const float* ea     = (const float*)d_in[1];
  const float* W0     = (const float*)d_in[2];
  const float* b0     = (const float*)d_in[3];
  const float* We1    = (const float*)d_in[4];
  const float* be1    = (const float*)d_in[5];
  const float* We2    = (const float*)d_in[6];
  const float* be2    = (const float*)d_in[7];
  const float* root   = (const float*)d_in[8];
  const float* conv_b = (const float*)d_in[9];
  const float* gwih   = (const float*)d_in[10];
  const float* gwhh   = (const float*)d_in[11];
  const float* gbih   = (const float*)d_in[12];
  const float* gbhh   = (const float*)d_in[13];
  const float* s2swi  = (const float*)d_in[14];
  const float* s2swh  = (const float*)d_in[15];
  const float* s2sbi  = (const float*)d_in[16];
  const float* s2sbh  = (const float*)d_in[17];
  const float* memwi  = (const float*)d_in[18];
  const float* membi  = (const float*)d_in[20];
  const float* membh  = (const float*)d_in[21];
  const float* W1     = (const float*)d_in[22];
  const float* b1     = (const float*)d_in[23];
  const float* W2     = (const float*)d_in[24];
  const float* b2     = (const float*)d_in[25];
  const int*   eidx   = (const int*)d_in[26];
  const int*   nonr   = (const int*)d_in[27];
  const int* src = eidx, *dst = eidx + NE;
  float* y = (float*)d_out;

  char* wsb = (char*)d_ws;
  size_t off = 0;
  auto alloc = [&](size_t bytes){ size_t o = off; off += (bytes + 255) & ~(size_t)255; return o; };
  float* out    = (float*)(wsb + alloc((size_t)NN*64*4));
  float* h      = (float*)(wsb + alloc((size_t)NN*64*4));
  float* agg    = (float*)(wsb + alloc((size_t)NN*64*4));
  float* deg    = (float*)(wsb + alloc((size_t)NN*4));
  float* st     = (float*)(wsb + alloc(7*256*4));
  float* hid    = (float*)(wsb + alloc((size_t)NT*128*4));
  ushortT* Rbf  = (ushortT*)(wsb + alloc((size_t)NE*128*2));
  ushortT* We2bf= (ushortT*)(wsb + alloc((size_t)4096*128*2));
  ushortT* wmem = (ushortT*)(wsb + alloc((size_t)1536*384*2));
  ushortT* w1bf = (ushortT*)(wsb + alloc((size_t)128*384*2));
  ushortT* zbf  = (ushortT*)(wsb + alloc((size_t)NT*384*2));
  ushortT* hmbf = (ushortT*)(wsb + alloc((size_t)NT*384*2));
  ushortT* outbf= (ushortT*)(wsb + alloc((size_t)NN*64*2));
  ushortT* hbf  = (ushortT*)(wsb + alloc((size_t)NN*64*2));
  ushortT* gwihbf = (ushortT*)(wsb + alloc((size_t)192*64*2));
  ushortT* gwhhbf = (ushortT*)(wsb + alloc((size_t)192*64*2));
  ushortT* rootTbf= (ushortT*)(wsb + alloc((size_t)64*64*2));
  (void)ws_size; (void)n_in; (void)in_sizes; (void)out_size;

  hipMemsetAsync(deg, 0, (size_t)NN*4, stream);
  hipMemsetAsync(st, 0, 7*256*4, stream);
  hipMemsetAsync(agg, 0, (size_t)NN*64*4, stream);
  k_lin0<<<NN*64/256, 256, 0, stream>>>(x, W0, b0, out, h, outbf, hbf);
  k_deg<<<(NE+255)/256, 256, 0, stream>>>(dst, deg);
  k_edgemlp<<<NE*128/256, 256, 0, stream>>>(ea, We1, be1, Rbf);
  k_prep<<<(PREP_T+255)/256, 256, 0, stream>>>(We2, memwi, W1, gwih, gwhh, root,
                                               We2bf, wmem, w1bf, gwihbf, gwhhbf, rootTbf);

  for (int it = 0; it < 6; ++it){
    k_fmsg<<<dim3((NE + EB - 1)/EB, 2), 256, 0, stream>>>(Rbf, We2bf, be2, outbf, src, dst, agg);
    k_gru2<<<NN/32, 256, 0, stream>>>(agg, deg, rootTbf, conv_b, gwihbf, gwhhbf,
                                      gbih, gbhh, out, h, outbf, hbf);
  }

  for (int it = 0; it < 6; ++it){
    k_s2s2<<<(NN + 127)/128, 256, 0, stream>>>(out, s2swi, s2swh, s2sbi, s2sbh, st, it);
  }

  k_z<<<NT*384/256, 256, 0, stream>>>(out, st, nonr, zbf);
  k_mem2<<<dim3(32, 6), 256, 0, stream>>>(zbf, wmem, membi, membh, hmbf);
  k_fin1<<<dim3(32, 2), 256, 0, stream>>>(hmbf, w1bf, b1, hid);
  k_fin2<<<32, 256, 0, stream>>>(hid, W2, b2, y);
}

// Round 13
// 674.376 us; speedup vs baseline: 1.6021x; 1.6021x over previous
//
#include <hip/hip_runtime.h>
#include <hip/hip_bf16.h>

#define NN 20000
#define NE 60000
#define NT 1024

typedef unsigned short ushortT;
typedef __attribute__((ext_vector_type(8))) short bf16x8;
typedef __attribute__((ext_vector_type(8))) unsigned short u16x8;
typedef __attribute__((ext_vector_type(4))) float f32x4;

__device__ __forceinline__ float sigm(float x){ return 1.0f/(1.0f+expf(-x)); }
__device__ __forceinline__ float bfu2f(ushortT u){ return __uint_as_float(((unsigned)u)<<16); }
__device__ __forceinline__ ushortT f2bfu(float f){
  __hip_bfloat16 b = __float2bfloat16(f);
  return *reinterpret_cast<ushortT*>(&b);
}

// ---------------- lin0: out = relu(x @ W0.T + b0); h = out ----------------
__global__ void k_lin0(const float* __restrict__ x, const float* __restrict__ W0,
                       const float* __restrict__ b0, float* __restrict__ out,
                       float* __restrict__ h, ushortT* __restrict__ outbf,
                       ushortT* __restrict__ hbf){
  int idx = blockIdx.x*256 + threadIdx.x;       // N*64 exact
  int n = idx >> 6, j = idx & 63;
  float a = b0[j] + x[n*3+0]*W0[j*3+0] + x[n*3+1]*W0[j*3+1] + x[n*3+2]*W0[j*3+2];
  a = fmaxf(a, 0.0f);
  out[idx] = a; h[idx] = a;
  ushortT u = f2bfu(a);
  outbf[idx] = u; hbf[idx] = u;
}

__global__ void k_deg(const int* __restrict__ dst, float* __restrict__ deg){
  int e = blockIdx.x*256 + threadIdx.x;
  if (e < NE) atomicAdd(&deg[dst[e]], 1.0f);
}

// ------------- edge MLP hidden: R = relu(edge_attr @ We1.T + be1) (bf16) ----
__global__ void k_edgemlp(const float* __restrict__ ea, const float* __restrict__ We1,
                          const float* __restrict__ be1, ushortT* __restrict__ Rbf){
  int idx = blockIdx.x*256 + threadIdx.x;       // E*128 exact
  int e = idx >> 7, k = idx & 127;
  float a = be1[k];
  #pragma unroll
  for (int j = 0; j < 7; ++j) a += ea[e*7+j]*We1[k*7+j];
  Rbf[idx] = f2bfu(fmaxf(a, 0.0f));
}

// ------------- fused weight prep: bf16 cvts + rootT transpose -------------
#define PREP_T ((4096*128) + (1536*384) + (128*384) + (192*64) + (192*64) + (64*64))
__global__ void k_prep(const float* __restrict__ We2, const float* __restrict__ memwi,
                       const float* __restrict__ W1, const float* __restrict__ gwih,
                       const float* __restrict__ gwhh, const float* __restrict__ root,
                       ushortT* __restrict__ We2bf, ushortT* __restrict__ wmem,
                       ushortT* __restrict__ w1bf, ushortT* __restrict__ gwihbf,
                       ushortT* __restrict__ gwhhbf, ushortT* __restrict__ rootTbf){
  int idx = blockIdx.x*256 + threadIdx.x;
  if (idx < 4096*128){ We2bf[idx] = f2bfu(We2[idx]); return; }
  idx -= 4096*128;
  if (idx < 1536*384){ wmem[idx] = f2bfu(memwi[idx]); return; }
  idx -= 1536*384;
  if (idx < 128*384){ w1bf[idx] = f2bfu(W1[idx]); return; }
  idx -= 128*384;
  if (idx < 192*64){ gwihbf[idx] = f2bfu(gwih[idx]); return; }
  idx -= 192*64;
  if (idx < 192*64){ gwhhbf[idx] = f2bfu(gwhh[idx]); return; }
  idx -= 192*64;
  if (idx < 64*64){ int d = idx >> 6, j = idx & 63; rootTbf[j*64 + d] = f2bfu(root[idx]); }
}

// ---------- fused NNConv message: agg[dst[e]] += out[src[e]] @ (R[e]@We2^T + be2) ----------
// Grid (235, 2). 32 phases x 2 d-tiles: per phase {vmcnt(0) -> s_barrier ->
// stage tiles 2p+2,2p+3 -> ds_read+MFMA tile 2p -> ds_read+MFMA tile 2p+1}.
// 4-deep LDS rotation: stage targets (2p+2)&3,(2p+3)&3, reads use (2p)&3,(2p+1)&3
// (disjoint; staged bufs last read at phase p-1, complete before this barrier).
// The vmcnt(0) drains loads issued a FULL phase earlier -> nearly free.
// Pre-swizzled source (kslot ^= row&7) keeps ds_read_b128 conflict-free.
// LDS ~74.8KB -> 2 blocks/CU.
#define EB 256
__global__ __launch_bounds__(256, 2) void k_fmsg(
    const ushortT* __restrict__ Rbf, const ushortT* __restrict__ We2bf,
    const float* __restrict__ be2, const ushortT* __restrict__ outbf,
    const int* __restrict__ src, const int* __restrict__ dst,
    float* __restrict__ agg)
{
  __shared__ ushortT o_sT[64][264];    // bf16 out[src[e]] transposed [d][edge]
  __shared__ ushortT bufB[4][4096];    // 32 rows x 128 k bf16 (8KB each), swizzled slots
  __shared__ float   be2q[64][32];     // be2 slice for this fh
  __shared__ int     dst_s[EB];

  int tid = threadIdx.x;
  int e0 = blockIdx.x * EB;
  int fh = blockIdx.y;                 // 0..1
  int w = tid >> 6, lane = tid & 63;
  int l15 = lane & 15, g = lane >> 4;  // g in 0..3

  auto stage = [&](int d, int b){
    #pragma unroll
    for (int i = 0; i < 2; ++i){
      int s = (w*2 + i)*64 + lane;          // 0..511
      int row = s >> 4, kslot = s & 15;
      const ushortT* gp = We2bf + (size_t)((d<<6) + (fh<<5) + row)*128 + ((kslot ^ (row & 7))<<3);
      __builtin_amdgcn_global_load_lds(
          (const __attribute__((address_space(1))) void*)gp,
          (__attribute__((address_space(3))) void*)&bufB[b][(size_t)s*8], 16, 0, 0);
    }
  };
  // prologue stages tiles 0,1 (drained once by the prologue __syncthreads)
  stage(0, 0); stage(1, 1);

  // ---- prologue: dst + o gather (bf16, transposed), be2 slice ----
  {
    int ge = e0 + tid;
    int sn = src[ge];                  // ge < 60160 < 2*NE: stays inside eidx alloc
    dst_s[tid] = (ge < NE) ? dst[ge] : -1;
    const ushortT* op = outbf + (size_t)sn*64;
    #pragma unroll
    for (int i = 0; i < 8; ++i){
      u16x8 v = *reinterpret_cast<const u16x8*>(op + i*8);
      #pragma unroll
      for (int j = 0; j < 8; ++j) o_sT[i*8+j][tid] = v[j];
    }
  }
  #pragma unroll
  for (int i = 0; i < 8; ++i){
    int idx = tid*8 + i;
    int dd = idx >> 5, cc = idx & 31;
    be2q[dd][cc] = be2[(dd<<6) + (fh<<5) + cc];
  }

  // A fragments: R rows for this wave's 64 edges, all K=128 (4 k-steps)
  bf16x8 af[4][4];
  #pragma unroll
  for (int t = 0; t < 4; ++t){
    #pragma unroll
    for (int ks = 0; ks < 4; ++ks){
      int ge = e0 + w*64 + t*16 + l15;
      bf16x8 z = {0,0,0,0,0,0,0,0};
      af[t][ks] = (ge < NE) ? *reinterpret_cast<const bf16x8*>(Rbf + (size_t)ge*128 + ks*32 + g*8) : z;
    }
  }

  f32x4 msg[4][2];
  #pragma unroll
  for (int t = 0; t < 4; ++t){
    #pragma unroll
    for (int q = 0; q < 2; ++q){ msg[t][q][0]=0.f; msg[t][q][1]=0.f; msg[t][q][2]=0.f; msg[t][q][3]=0.f; }
  }
  __syncthreads();   // prologue visibility (one-time drain; tiles 0,1 complete)

  auto compute = [&](int d, int b){
    bf16x8 bf0[4], bf1[4];
    #pragma unroll
    for (int ks = 0; ks < 4; ++ks){
      bf0[ks] = *reinterpret_cast<const bf16x8*>(&bufB[b][ (l15)*128    + ((((ks<<2)+g) ^ (l15&7))<<3) ]);
      bf1[ks] = *reinterpret_cast<const bf16x8*>(&bufB[b][ (16+l15)*128 + ((((ks<<2)+g) ^ (l15&7))<<3) ]);
    }
    f32x4 ac[4][2];
    #pragma unroll
    for (int t = 0; t < 4; ++t){
      #pragma unroll
      for (int q = 0; q < 2; ++q){ ac[t][q][0]=0.f; ac[t][q][1]=0.f; ac[t][q][2]=0.f; ac[t][q][3]=0.f; }
    }
    __builtin_amdgcn_s_setprio(1);
    #pragma unroll
    for (int ks = 0; ks < 4; ++ks){
      #pragma unroll
      for (int t = 0; t < 4; ++t){
        ac[t][0] = __builtin_amdgcn_mfma_f32_16x16x32_bf16(af[t][ks], bf0[ks], ac[t][0], 0, 0, 0);
        ac[t][1] = __builtin_amdgcn_mfma_f32_16x16x32_bf16(af[t][ks], bf1[ks], ac[t][1], 0, 0, 0);
      }
    }
    __builtin_amdgcn_s_setprio(0);
    float be2v0 = be2q[d][l15];
    float be2v1 = be2q[d][16 + l15];
    #pragma unroll
    for (int t = 0; t < 4; ++t){
      ushort4 ou = *reinterpret_cast<const ushort4*>(&o_sT[d][w*64 + t*16 + g*4]);
      float o0 = bfu2f(ou.x), o1 = bfu2f(ou.y), o2 = bfu2f(ou.z), o3 = bfu2f(ou.w);
      msg[t][0][0] += o0*(ac[t][0][0] + be2v0);
      msg[t][0][1] += o1*(ac[t][0][1] + be2v0);
      msg[t][0][2] += o2*(ac[t][0][2] + be2v0);
      msg[t][0][3] += o3*(ac[t][0][3] + be2v0);
      msg[t][1][0] += o0*(ac[t][1][0] + be2v1);
      msg[t][1][1] += o1*(ac[t][1][1] + be2v1);
      msg[t][1][2] += o2*(ac[t][1][2] + be2v1);
      msg[t][1][3] += o3*(ac[t][1][3] + be2v1);
    }
  };

  // 32 phases of 2 d-tiles; one barrier per phase
  for (int p = 0; p < 32; ++p){
    int d0 = p << 1;
    asm volatile("s_waitcnt vmcnt(0)" ::: "memory");
    __builtin_amdgcn_sched_barrier(0);
    __builtin_amdgcn_s_barrier();
    __builtin_amdgcn_sched_barrier(0);
    if (p < 31){
      stage(d0 + 2, (d0 + 2) & 3);
      stage(d0 + 3, (d0 + 3) & 3);
    }
    compute(d0,     d0 & 3);
    compute(d0 + 1, (d0 + 1) & 3);
  }

  #pragma unroll
  for (int t = 0; t < 4; ++t){
    #pragma unroll
    for (int r = 0; r < 4; ++r){
      int el = w*64 + t*16 + g*4 + r;
      int tn = dst_s[el];
      if (tn >= 0){
        atomicAdd(&agg[(size_t)tn*64 + (fh<<5) + l15],      msg[t][0][r]);
        atomicAdd(&agg[(size_t)tn*64 + (fh<<5) + 16 + l15], msg[t][1][r]);
      }
    }
  }
}

// ------------- NNConv epilogue + GRU cell via MFMA (32 nodes/block, grid 625) -------------
__global__ __launch_bounds__(256) void k_gru2(
    const float* __restrict__ agg_in, const float* __restrict__ deg,
    const ushortT* __restrict__ rootT, const float* __restrict__ conv_b,
    const ushortT* __restrict__ wih, const ushortT* __restrict__ whh,
    const float* __restrict__ bih, const float* __restrict__ bhh,
    float* __restrict__ out, float* __restrict__ h,
    ushortT* __restrict__ outbf, ushortT* __restrict__ hbf)
{
  __shared__ ushortT mbf[32*64];
  float* agg = const_cast<float*>(agg_in);
  int tid = threadIdx.x;
  int w = tid >> 6, lane = tid & 63;
  int l15 = lane & 15, g = lane >> 4;
  int n0 = blockIdx.x * 32;
  int j = w*16 + l15;

  // ---- stage 1: root transform ----
  f32x4 acc1[2];
  #pragma unroll
  for (int rt = 0; rt < 2; ++rt){ acc1[rt][0]=0.f; acc1[rt][1]=0.f; acc1[rt][2]=0.f; acc1[rt][3]=0.f; }
  bf16x8 ah[2][2];
  #pragma unroll
  for (int ks = 0; ks < 2; ++ks){
    bf16x8 b = *reinterpret_cast<const bf16x8*>(rootT + (size_t)j*64 + g*8 + ks*32);
    #pragma unroll
    for (int rt = 0; rt < 2; ++rt){
      bf16x8 a = *reinterpret_cast<const bf16x8*>(outbf + (size_t)(n0 + rt*16 + l15)*64 + g*8 + ks*32);
      acc1[rt] = __builtin_amdgcn_mfma_f32_16x16x32_bf16(a, b, acc1[rt], 0, 0, 0);
      ah[rt][ks] = *reinterpret_cast<const bf16x8*>(hbf + (size_t)(n0 + rt*16 + l15)*64 + g*8 + ks*32);
    }
  }
  {
    float cb = conv_b[j];
    #pragma unroll
    for (int rt = 0; rt < 2; ++rt){
      #pragma unroll
      for (int r = 0; r < 4; ++r){
        int row = rt*16 + g*4 + r;
        int node = n0 + row;
        float inv = 1.0f/fmaxf(deg[node], 1.0f);
        float mval = fmaxf(acc1[rt][r] + agg[(size_t)node*64 + j]*inv + cb, 0.0f);
        agg[(size_t)node*64 + j] = 0.0f;
        int gran = (j >> 3) ^ (row & 7);
        mbf[row*64 + (gran<<3) + (j & 7)] = f2bfu(mval);
      }
    }
  }
  __syncthreads();   // mbf visible; outbf/hbf reads drained

  // ---- stage 2: gates ----
  f32x4 gx[3][2], gh[3][2];
  #pragma unroll
  for (int ci = 0; ci < 3; ++ci){
    #pragma unroll
    for (int rt = 0; rt < 2; ++rt){
      gx[ci][rt][0]=0.f; gx[ci][rt][1]=0.f; gx[ci][rt][2]=0.f; gx[ci][rt][3]=0.f;
      gh[ci][rt][0]=0.f; gh[ci][rt][1]=0.f; gh[ci][rt][2]=0.f; gh[ci][rt][3]=0.f;
    }
  }
  #pragma unroll
  for (int ks = 0; ks < 2; ++ks){
    bf16x8 am[2];
    #pragma unroll
    for (int rt = 0; rt < 2; ++rt){
      int arow = rt*16 + l15;
      int agran = (g + ks*4) ^ (l15 & 7);
      am[rt] = *reinterpret_cast<const bf16x8*>(&mbf[arow*64 + (agran<<3)]);
    }
    #pragma unroll
    for (int ci = 0; ci < 3; ++ci){
      int c = (w + ci*4)*16 + l15;     // abs gate column (ci = gate)
      bf16x8 bx = *reinterpret_cast<const bf16x8*>(wih + (size_t)c*64 + g*8 + ks*32);
      bf16x8 bh = *reinterpret_cast<const bf16x8*>(whh + (size_t)c*64 + g*8 + ks*32);
      #pragma unroll
      for (int rt = 0; rt < 2; ++rt){
        gx[ci][rt] = __builtin_amdgcn_mfma_f32_16x16x32_bf16(am[rt], bx, gx[ci][rt], 0, 0, 0);
        gh[ci][rt] = __builtin_amdgcn_mfma_f32_16x16x32_bf16(ah[rt][ks], bh, gh[ci][rt], 0, 0, 0);
      }
    }
  }
  // ---- epilogue: GRU update, fully in-register ----
  float bxr = bih[j], bxz = bih[64+j], bxn = bih[128+j];
  float bhr = bhh[j], bhz = bhh[64+j], bhn = bhh[128+j];
  #pragma unroll
  for (int rt = 0; rt < 2; ++rt){
    #pragma unroll
    for (int r = 0; r < 4; ++r){
      int node = n0 + rt*16 + g*4 + r;
      float gxr = gx[0][rt][r] + bxr, gxz = gx[1][rt][r] + bxz, gxn = gx[2][rt][r] + bxn;
      float ghr = gh[0][rt][r] + bhr, ghz = gh[1][rt][r] + bhz, ghn = gh[2][rt][r] + bhn;
      float rr = sigm(gxr + ghr), zz = sigm(gxz + ghz);
      float nn_ = tanhf(gxn + rr*ghn);
      float hold = h[(size_t)node*64 + j];
      float hn = (1.0f - zz)*nn_ + zz*hold;
      h[(size_t)node*64 + j]   = hn;
      out[(size_t)node*64 + j] = hn;
      ushortT u = f2bfu(hn);
      outbf[(size_t)node*64 + j] = u;
      hbf[(size_t)node*64 + j]   = u;
    }
  }
}

// ------------- Set2Set: fused LSTM cell + attention, 7-slot state pipeline -------------
__global__ void k_s2s2(const float* __restrict__ out, const float* __restrict__ wi,
                       const float* __restrict__ wh, const float* __restrict__ bi,
                       const float* __restrict__ bh, float* __restrict__ st, int it){
  const float* sr = st + it*256;
  float* sw = st + (it+1)*256;
  __shared__ float qs[128], hsl[64], gg[256];
  __shared__ float ob[128*65], wl[128], zred[128], part[256];
  int tid = threadIdx.x;      // 256
  int n0 = blockIdx.x * 128;

  // ---- cell (computed redundantly by every block) ----
  if (tid < 64) qs[tid] = sr[tid];
  else if (tid < 128){
    float Z = sr[192];
    qs[tid] = (Z != 0.0f) ? sr[128 + (tid-64)]/Z : 0.0f;
  }
  __syncthreads();
  {
    float a = bi[tid] + bh[tid];
    #pragma unroll 8
    for (int k = 0; k < 128; ++k) a += qs[k]*wi[tid*128 + k];
    #pragma unroll 8
    for (int k = 0; k < 64;  ++k) a += sr[k]*wh[tid*64 + k];
    gg[tid] = a;
  }
  __syncthreads();
  if (tid < 64){
    float iv = sigm(gg[tid]), fv = sigm(gg[64+tid]);
    float gv = tanhf(gg[128+tid]), ov = sigm(gg[192+tid]);
    float c = fv*sr[64+tid] + iv*gv;
    float hnew = ov*tanhf(c);
    hsl[tid] = hnew;
    if (blockIdx.x == 0){ sw[64+tid] = c; sw[tid] = hnew; }
  }
  // ---- attention over this block's 128 nodes ----
  #pragma unroll
  for (int rr = 0; rr < 8; ++rr){
    int idx = rr*1024 + tid*4;
    int nl = idx >> 6, jj = idx & 63;
    float4 v = make_float4(0.f,0.f,0.f,0.f);
    if (n0 + nl < NN) v = *reinterpret_cast<const float4*>(&out[(size_t)(n0+nl)*64 + jj]);
    ob[nl*65 + jj + 0] = v.x; ob[nl*65 + jj + 1] = v.y;
    ob[nl*65 + jj + 2] = v.z; ob[nl*65 + jj + 3] = v.w;
  }
  __syncthreads();
  if (tid < 128){
    float e = 0.f;
    #pragma unroll 8
    for (int jj = 0; jj < 64; ++jj) e += ob[tid*65 + jj]*hsl[jj];
    float wv = (n0 + tid < NN) ? expf(e) : 0.f;
    wl[tid] = wv; zred[tid] = wv;
  }
  __syncthreads();
  if (tid < 64) zred[tid] += zred[tid + 64];
  __syncthreads();
  if (tid < 32) zred[tid] += zred[tid + 32];
  __syncthreads();
  if (tid < 16) zred[tid] += zred[tid + 16];
  __syncthreads();
  if (tid < 8) zred[tid] += zred[tid + 8];
  __syncthreads();
  if (tid == 0){
    float z = zred[0]+zred[1]+zred[2]+zred[3]+zred[4]+zred[5]+zred[6]+zred[7];
    atomicAdd(&sw[192], z);
  }
  {
    int gq = tid >> 6, d = tid & 63;
    float acc = 0.f;
    #pragma unroll 8
    for (int i = 0; i < 32; ++i){
      int nl = gq*32 + i;
      acc += wl[nl]*ob[nl*65 + d];
    }
    part[tid] = acc;
  }
  __syncthreads();
  if (tid < 64)
    atomicAdd(&sw[128 + tid], part[tid] + part[64+tid] + part[128+tid] + part[192+tid]);
}

// ------------- head -------------
__global__ void k_z(const float* __restrict__ out, const float* __restrict__ st,
                    const int* __restrict__ nonring, ushortT* __restrict__ zbf){
  const float* s6 = st + 6*256;
  int idx = blockIdx.x*256 + threadIdx.x;         // T*384 exact
  int t = idx / 384, c = idx % 384;
  float v;
  if (c < 256){
    int a = c*16 + (t >> 6);
    int node = nonring[a];
    v = out[(size_t)node*64 + (t & 63)];
  } else {
    int pi = t >> 3;                              // pool index (quirky repeat)
    v = (pi < 64) ? s6[pi] : s6[128 + (pi - 64)] / s6[192];
  }
  zbf[idx] = f2bfu(v);
}

// memory LSTM via MFMA: gates = zbf @ wmem^T (+biases); hm = sig(o)*tanh(sig(i)*tanh(g))
__global__ __launch_bounds__(256) void k_mem2(
    const ushortT* __restrict__ zbf, const ushortT* __restrict__ wmem,
    const float* __restrict__ membi, const float* __restrict__ membh,
    ushortT* __restrict__ hmbf){
  int tid = threadIdx.x;
  int w = tid >> 6, lane = tid & 63;
  int l15 = lane & 15, g = lane >> 4;
  int m0 = blockIdx.x * 32;
  int jw = blockIdx.y * 64 + w * 16;

  f32x4 ai[2], ag[2], ao[2];
  #pragma unroll
  for (int m = 0; m < 2; ++m){
    #pragma unroll
    for (int r = 0; r < 4; ++r){ ai[m][r]=0.f; ag[m][r]=0.f; ao[m][r]=0.f; }
  }
  const ushortT* a0p = zbf + (size_t)(m0 + l15)*384 + g*8;
  const ushortT* a1p = zbf + (size_t)(m0 + 16 + l15)*384 + g*8;
  const ushortT* bip = wmem + (size_t)(jw + l15)*384 + g*8;
  const ushortT* bgp = wmem + (size_t)(768 + jw + l15)*384 + g*8;
  const ushortT* bop = wmem + (size_t)(1152 + jw + l15)*384 + g*8;
  #pragma unroll
  for (int ks = 0; ks < 12; ++ks){
    bf16x8 a0 = *reinterpret_cast<const bf16x8*>(a0p + ks*32);
    bf16x8 a1 = *reinterpret_cast<const bf16x8*>(a1p + ks*32);
    bf16x8 bi = *reinterpret_cast<const bf16x8*>(bip + ks*32);
    bf16x8 bg = *reinterpret_cast<const bf16x8*>(bgp + ks*32);
    bf16x8 bo = *reinterpret_cast<const bf16x8*>(bop + ks*32);
    ai[0] = __builtin_amdgcn_mfma_f32_16x16x32_bf16(a0, bi, ai[0], 0, 0, 0);
    ai[1] = __builtin_amdgcn_mfma_f32_16x16x32_bf16(a1, bi, ai[1], 0, 0, 0);
    ag[0] = __builtin_amdgcn_mfma_f32_16x16x32_bf16(a0, bg, ag[0], 0, 0, 0);
    ag[1] = __builtin_amdgcn_mfma_f32_16x16x32_bf16(a1, bg, ag[1], 0, 0, 0);
    ao[0] = __builtin_amdgcn_mfma_f32_16x16x32_bf16(a0, bo, ao[0], 0, 0, 0);
    ao[1] = __builtin_amdgcn_mfma_f32_16x16x32_bf16(a1, bo, ao[1], 0, 0, 0);
  }
  int j = jw + l15;
  float bI = membi[j]        + membh[j];
  float bG = membi[768 + j]  + membh[768 + j];
  float bO = membi[1152 + j] + membh[1152 + j];
  #pragma unroll
  for (int m = 0; m < 2; ++m){
    #pragma unroll
    for (int r = 0; r < 4; ++r){
      int t = m0 + m*16 + g*4 + r;
      float gi = ai[m][r] + bI;
      float gG = ag[m][r] + bG;
      float go = ao[m][r] + bO;
      float cm = sigm(gi)*tanhf(gG);
      hmbf[(size_t)t*384 + j] = f2bfu(sigm(go)*tanhf(cm));
    }
  }
}

// fin stage 1 via MFMA: hid = relu(hm @ W1^T + b1)  [1024 x 128] f32
__global__ __launch_bounds__(256) void k_fin1(
    const ushortT* __restrict__ hmbf, const ushortT* __restrict__ w1bf,
    const float* __restrict__ b1, float* __restrict__ hid){
  int tid = threadIdx.x;
  int w = tid >> 6, lane = tid & 63;
  int l15 = lane & 15, g = lane >> 4;
  int m0 = blockIdx.x * 32;
  int cw = blockIdx.y * 64 + w * 16;

  f32x4 acc[2];
  #pragma unroll
  for (int m = 0; m < 2; ++m){
    #pragma unroll
    for (int r = 0; r < 4; ++r) acc[m][r] = 0.f;
  }
  const ushortT* a0p = hmbf + (size_t)(m0 + l15)*384 + g*8;
  const ushortT* a1p = hmbf + (size_t)(m0 + 16 + l15)*384 + g*8;
  const ushortT* bp  = w1bf + (size_t)(cw + l15)*384 + g*8;
  #pragma unroll
  for (int ks = 0; ks < 12; ++ks){
    bf16x8 a0 = *reinterpret_cast<const bf16x8*>(a0p + ks*32);
    bf16x8 a1 = *reinterpret_cast<const bf16x8*>(a1p + ks*32);
    bf16x8 b  = *reinterpret_cast<const bf16x8*>(bp + ks*32);
    acc[0] = __builtin_amdgcn_mfma_f32_16x16x32_bf16(a0, b, acc[0], 0, 0, 0);
    acc[1] = __builtin_amdgcn_mfma_f32_16x16x32_bf16(a1, b, acc[1], 0, 0, 0);
  }
  int c = cw + l15;
  float bv = b1[c];
  #pragma unroll
  for (int m = 0; m < 2; ++m){
    #pragma unroll
    for (int r = 0; r < 4; ++r){
      int t = m0 + m*16 + g*4 + r;
      hid[(size_t)t*128 + c] = fmaxf(acc[m][r] + bv, 0.0f);
    }
  }
}

// fin stage 2: y[t][j] = b2[j] + hid[t] . W2[j]   (j < 6)
__global__ void k_fin2(const float* __restrict__ hid, const float* __restrict__ W2,
                       const float* __restrict__ b2, float* __restrict__ y){
  int tid = threadIdx.x;                 // 256
  int t = blockIdx.x*32 + (tid >> 3);    // grid 32 exact
  int j = tid & 7;
  if (j >= 6) return;
  float a = b2[j];
  const float* hp = hid + (size_t)t*128;
  const float* wp = W2 + j*128;
  #pragma unroll 8
  for (int k = 0; k < 128; ++k) a += hp[k]*wp[k];
  y[t*6 + j] = a;
}

extern "C" void kernel_launch(void* const* d_in, const int* in_sizes, int n_in,
                              void* d_out, int out_size, void* d_ws, size_t ws_size,
                              hipStream_t stream){
  const float* x      = (const float*)d_in[0];
  const float* ea     = (const float*)d_in[1];
  const float* W0     = (const float*)d_in[2];
  const float* b0     = (const float*)d_in[3];
  const float* We1    = (const float*)d_in[4];
  const float* be1    = (const float*)d_in[5];
  const float* We2    = (const float*)d_in[6];
  const float* be2    = (const float*)d_in[7];
  const float* root   = (const float*)d_in[8];
  const float* conv_b = (const float*)d_in[9];
  const float* gwih   = (const float*)d_in[10];
  const float* gwhh   = (const float*)d_in[11];
  const float* gbih   = (const float*)d_in[12];
  const float* gbhh   = (const float*)d_in[13];
  const float* s2swi  = (const float*)d_in[14];
  const float* s2swh  = (const float*)d_in[15];
  const float* s2sbi  = (const float*)d_in[16];
  const float* s2sbh  = (const float*)d_in[17];
  const float* memwi  = (const float*)d_in[18];
  const float* membi  = (const float*)d_in[20];
  const float* membh  = (const float*)d_in[21];
  const float* W1     = (const float*)d_in[22];
  const float* b1     = (const float*)d_in[23];
  const float* W2     = (const float*)d_in[24];
  const float* b2     = (const float*)d_in[25];
  const int*   eidx   = (const int*)d_in[26];
  const int*   nonr   = (const int*)d_in[27];
  const int* src = eidx, *dst = eidx + NE;
  float* y = (float*)d_out;

  char* wsb = (char*)d_ws;
  size_t off = 0;
  auto alloc = [&](size_t bytes){ size_t o = off; off += (bytes + 255) & ~(size_t)255; return o; };
  float* out    = (float*)(wsb + alloc((size_t)NN*64*4));
  float* h      = (float*)(wsb + alloc((size_t)NN*64*4));
  float* agg    = (float*)(wsb + alloc((size_t)NN*64*4));
  float* deg    = (float*)(wsb + alloc((size_t)NN*4));
  float* st     = (float*)(wsb + alloc(7*256*4));
  float* hid    = (float*)(wsb + alloc((size_t)NT*128*4));
  ushortT* Rbf  = (ushortT*)(wsb + alloc((size_t)NE*128*2));
  ushortT* We2bf= (ushortT*)(wsb + alloc((size_t)4096*128*2));
  ushortT* wmem = (ushortT*)(wsb + alloc((size_t)1536*384*2));
  ushortT* w1bf = (ushortT*)(wsb + alloc((size_t)128*384*2));
  ushortT* zbf  = (ushortT*)(wsb + alloc((size_t)NT*384*2));
  ushortT* hmbf = (ushortT*)(wsb + alloc((size_t)NT*384*2));
  ushortT* outbf= (ushortT*)(wsb + alloc((size_t)NN*64*2));
  ushortT* hbf  = (ushortT*)(wsb + alloc((size_t)NN*64*2));
  ushortT* gwihbf = (ushortT*)(wsb + alloc((size_t)192*64*2));
  ushortT* gwhhbf = (ushortT*)(wsb + alloc((size_t)192*64*2));
  ushortT* rootTbf= (ushortT*)(wsb + alloc((size_t)64*64*2));
  (void)ws_size; (void)n_in; (void)in_sizes; (void)out_size;

  hipMemsetAsync(deg, 0, (size_t)NN*4, stream);
  hipMemsetAsync(st, 0, 7*256*4, stream);
  hipMemsetAsync(agg, 0, (size_t)NN*64*4, stream);
  k_lin0<<<NN*64/256, 256, 0, stream>>>(x, W0, b0, out, h, outbf, hbf);
  k_deg<<<(NE+255)/256, 256, 0, stream>>>(dst, deg);
  k_edgemlp<<<NE*128/256, 256, 0, stream>>>(ea, We1, be1, Rbf);
  k_prep<<<(PREP_T+255)/256, 256, 0, stream>>>(We2, memwi, W1, gwih, gwhh, root,
                                               We2bf, wmem, w1bf, gwihbf, gwhhbf, rootTbf);

  for (int it = 0; it < 6; ++it){
    k_fmsg<<<dim3((NE + EB - 1)/EB, 2), 256, 0, stream>>>(Rbf, We2bf, be2, outbf, src, dst, agg);
    k_gru2<<<NN/32, 256, 0, stream>>>(agg, deg, rootTbf, conv_b, gwihbf, gwhhbf,
                                      gbih, gbhh, out, h, outbf, hbf);
  }

  for (int it = 0; it < 6; ++it){
    k_s2s2<<<(NN + 127)/128, 256, 0, stream>>>(out, s2swi, s2swh, s2sbi, s2sbh, st, it);
  }

  k_z<<<NT*384/256, 256, 0, stream>>>(out, st, nonr, zbf);
  k_mem2<<<dim3(32, 6), 256, 0, stream>>>(zbf, wmem, membi, membh, hmbf);
  k_fin1<<<dim3(32, 2), 256, 0, stream>>>(hmbf, w1bf, b1, hid);
  k_fin2<<<32, 256, 0, stream>>>(hid, W2, b2, y);
}

// Round 14
// 669.843 us; speedup vs baseline: 1.6129x; 1.0068x over previous
//
#include <hip/hip_runtime.h>
#include <hip/hip_bf16.h>

#define NN 20000
#define NE 60000
#define NT 1024

typedef unsigned short ushortT;
typedef __attribute__((ext_vector_type(8))) short bf16x8;
typedef __attribute__((ext_vector_type(8))) unsigned short u16x8;
typedef __attribute__((ext_vector_type(4))) float f32x4;

__device__ __forceinline__ float sigm(float x){ return 1.0f/(1.0f+expf(-x)); }
__device__ __forceinline__ float bfu2f(ushortT u){ return __uint_as_float(((unsigned)u)<<16); }
__device__ __forceinline__ ushortT f2bfu(float f){
  __hip_bfloat16 b = __float2bfloat16(f);
  return *reinterpret_cast<ushortT*>(&b);
}

// ---------------- lin0: out = relu(x @ W0.T + b0); h = out ----------------
__global__ void k_lin0(const float* __restrict__ x, const float* __restrict__ W0,
                       const float* __restrict__ b0, float* __restrict__ out,
                       float* __restrict__ h, ushortT* __restrict__ outbf,
                       ushortT* __restrict__ hbf){
  int idx = blockIdx.x*256 + threadIdx.x;       // N*64 exact
  int n = idx >> 6, j = idx & 63;
  float a = b0[j] + x[n*3+0]*W0[j*3+0] + x[n*3+1]*W0[j*3+1] + x[n*3+2]*W0[j*3+2];
  a = fmaxf(a, 0.0f);
  out[idx] = a; h[idx] = a;
  ushortT u = f2bfu(a);
  outbf[idx] = u; hbf[idx] = u;
}

__global__ void k_deg(const int* __restrict__ dst, float* __restrict__ deg){
  int e = blockIdx.x*256 + threadIdx.x;
  if (e < NE) atomicAdd(&deg[dst[e]], 1.0f);
}

// ------------- edge MLP hidden: R = relu(edge_attr @ We1.T + be1) (bf16) ----
__global__ void k_edgemlp(const float* __restrict__ ea, const float* __restrict__ We1,
                          const float* __restrict__ be1, ushortT* __restrict__ Rbf){
  int idx = blockIdx.x*256 + threadIdx.x;       // E*128 exact
  int e = idx >> 7, k = idx & 127;
  float a = be1[k];
  #pragma unroll
  for (int j = 0; j < 7; ++j) a += ea[e*7+j]*We1[k*7+j];
  Rbf[idx] = f2bfu(fmaxf(a, 0.0f));
}

// ------------- fused weight prep: bf16 cvts + rootT transpose -------------
#define PREP_T ((4096*128) + (1536*384) + (128*384) + (192*64) + (192*64) + (64*64))
__global__ void k_prep(const float* __restrict__ We2, const float* __restrict__ memwi,
                       const float* __restrict__ W1, const float* __restrict__ gwih,
                       const float* __restrict__ gwhh, const float* __restrict__ root,
                       ushortT* __restrict__ We2bf, ushortT* __restrict__ wmem,
                       ushortT* __restrict__ w1bf, ushortT* __restrict__ gwihbf,
                       ushortT* __restrict__ gwhhbf, ushortT* __restrict__ rootTbf){
  int idx = blockIdx.x*256 + threadIdx.x;
  if (idx < 4096*128){ We2bf[idx] = f2bfu(We2[idx]); return; }
  idx -= 4096*128;
  if (idx < 1536*384){ wmem[idx] = f2bfu(memwi[idx]); return; }
  idx -= 1536*384;
  if (idx < 128*384){ w1bf[idx] = f2bfu(W1[idx]); return; }
  idx -= 128*384;
  if (idx < 192*64){ gwihbf[idx] = f2bfu(gwih[idx]); return; }
  idx -= 192*64;
  if (idx < 192*64){ gwhhbf[idx] = f2bfu(gwhh[idx]); return; }
  idx -= 192*64;
  if (idx < 64*64){ int d = idx >> 6, j = idx & 63; rootTbf[j*64 + d] = f2bfu(root[idx]); }
}

// ---------- fused NNConv message: agg[dst[e]] += out[src[e]] @ (R[e]@We2^T + be2) ----------
// Grid (469). EB=128 edges x full 64 f per block. WAVE-AUTONOMOUS: wave w owns
// f-cols [w*16, w*16+16) and stages its own 16x128 B-tile into a private LDS
// region (2-deep rotation, 4 global_load_lds per stage). ZERO in-loop barriers:
// correctness needs only the wave-local counted s_waitcnt vmcnt(4) (prefetch
// distance 1 < depth 2; the staged buffer was last ds_read at step d-1, whose
// lgkmcnt-waited MFMAs precede this stage in program order). One prologue
// __syncthreads for the shared o_sT/be2q/dst_s. LDS ~66KB -> 2 blocks/CU.
#define EB 128
__global__ __launch_bounds__(256, 2) void k_fmsg(
    const ushortT* __restrict__ Rbf, const ushortT* __restrict__ We2bf,
    const float* __restrict__ be2, const ushortT* __restrict__ outbf,
    const int* __restrict__ src, const int* __restrict__ dst,
    float* __restrict__ agg)
{
  __shared__ ushortT o_sT[64][136];      // bf16 out[src[e]] transposed [d][edge] (17.4KB)
  __shared__ ushortT bufB[4][2][2048];   // per-wave [w][buf][16 rows x 128 k] (32KB)
  __shared__ float   be2q[64][64];       // be2 reshaped [d][f] (16KB)
  __shared__ int     dst_s[EB];

  int tid = threadIdx.x;
  int e0 = blockIdx.x * EB;
  int w = tid >> 6, lane = tid & 63;
  int l15 = lane & 15, g = lane >> 4;    // g in 0..3
  int f = (w << 4) + l15;                // this lane's f column

  auto stage = [&](int d, int b){
    #pragma unroll
    for (int i = 0; i < 4; ++i){
      int s = i*64 + lane;               // 0..255
      int row = s >> 4, kslot = s & 15;  // row 0..15 (f-col within wave tile)
      const ushortT* gp = We2bf + (size_t)((d<<6) + (w<<4) + row)*128 + ((kslot ^ (row & 7))<<3);
      __builtin_amdgcn_global_load_lds(
          (const __attribute__((address_space(1))) void*)gp,
          (__attribute__((address_space(3))) void*)&bufB[w][b][(size_t)i*512], 16, 0, 0);
    }
  };
  stage(0, 0);   // tile 0 into private buf 0

  // ---- prologue: dst + o gather (bf16, transposed; 2 threads/edge), be2 copy ----
  {
    int ei = tid >> 1;
    int ge = e0 + ei;
    int sn = (ge < NE) ? src[ge] : 0;
    if (tid < EB) dst_s[tid] = (e0 + tid < NE) ? dst[e0 + tid] : -1;
    int half = (tid & 1) * 32;
    const ushortT* op = outbf + (size_t)sn*64 + half;
    #pragma unroll
    for (int i = 0; i < 4; ++i){
      u16x8 v = *reinterpret_cast<const u16x8*>(op + i*8);
      #pragma unroll
      for (int j = 0; j < 8; ++j) o_sT[half + i*8 + j][ei] = v[j];
    }
  }
  #pragma unroll
  for (int i = 0; i < 4; ++i){
    int idx = tid*16 + i*4;                       // 4096 floats total
    *reinterpret_cast<float4*>(&be2q[0][0] + idx) =
        *reinterpret_cast<const float4*>(be2 + idx);
  }

  // A fragments: R rows for this block's 128 edges, all K=128 (4 k-steps)
  bf16x8 af[8][4];
  #pragma unroll
  for (int t = 0; t < 8; ++t){
    #pragma unroll
    for (int ks = 0; ks < 4; ++ks){
      int ge = e0 + t*16 + l15;
      bf16x8 z = {0,0,0,0,0,0,0,0};
      af[t][ks] = (ge < NE) ? *reinterpret_cast<const bf16x8*>(Rbf + (size_t)ge*128 + ks*32 + g*8) : z;
    }
  }

  f32x4 msg[8];
  #pragma unroll
  for (int t = 0; t < 8; ++t){ msg[t][0]=0.f; msg[t][1]=0.f; msg[t][2]=0.f; msg[t][3]=0.f; }
  __syncthreads();   // o_sT / be2q / dst_s visible (only barrier in the kernel)

  for (int d = 0; d < 64; ++d){
    if (d < 63) stage(d + 1, (d + 1) & 1);
    if (d < 63){
      asm volatile("s_waitcnt vmcnt(4)" ::: "memory");   // own stage(d) complete
    } else {
      asm volatile("s_waitcnt vmcnt(0)" ::: "memory");
    }
    __builtin_amdgcn_sched_barrier(0);
    int b = d & 1;
    // B fragments from private swizzled LDS region
    bf16x8 bf[4];
    #pragma unroll
    for (int ks = 0; ks < 4; ++ks)
      bf[ks] = *reinterpret_cast<const bf16x8*>(&bufB[w][b][ l15*128 + ((((ks<<2)+g) ^ (l15&7))<<3) ]);
    f32x4 ac[8];
    #pragma unroll
    for (int t = 0; t < 8; ++t){ ac[t][0]=0.f; ac[t][1]=0.f; ac[t][2]=0.f; ac[t][3]=0.f; }
    __builtin_amdgcn_s_setprio(1);
    #pragma unroll
    for (int ks = 0; ks < 4; ++ks){
      #pragma unroll
      for (int t = 0; t < 8; ++t)
        ac[t] = __builtin_amdgcn_mfma_f32_16x16x32_bf16(af[t][ks], bf[ks], ac[t], 0, 0, 0);
    }
    __builtin_amdgcn_s_setprio(0);
    float be2v = be2q[d][f];
    #pragma unroll
    for (int t = 0; t < 8; ++t){
      ushort4 ou = *reinterpret_cast<const ushort4*>(&o_sT[d][t*16 + g*4]);
      msg[t][0] += bfu2f(ou.x)*(ac[t][0] + be2v);
      msg[t][1] += bfu2f(ou.y)*(ac[t][1] + be2v);
      msg[t][2] += bfu2f(ou.z)*(ac[t][2] + be2v);
      msg[t][3] += bfu2f(ou.w)*(ac[t][3] + be2v);
    }
  }

  #pragma unroll
  for (int t = 0; t < 8; ++t){
    #pragma unroll
    for (int r = 0; r < 4; ++r){
      int el = t*16 + g*4 + r;
      int tn = dst_s[el];
      if (tn >= 0) atomicAdd(&agg[(size_t)tn*64 + f], msg[t][r]);
    }
  }
}

// ------------- NNConv epilogue + GRU cell via MFMA (32 nodes/block, grid 625) -------------
__global__ __launch_bounds__(256) void k_gru2(
    const float* __restrict__ agg_in, const float* __restrict__ deg,
    const ushortT* __restrict__ rootT, const float* __restrict__ conv_b,
    const ushortT* __restrict__ wih, const ushortT* __restrict__ whh,
    const float* __restrict__ bih, const float* __restrict__ bhh,
    float* __restrict__ out, float* __restrict__ h,
    ushortT* __restrict__ outbf, ushortT* __restrict__ hbf)
{
  __shared__ ushortT mbf[32*64];
  float* agg = const_cast<float*>(agg_in);
  int tid = threadIdx.x;
  int w = tid >> 6, lane = tid & 63;
  int l15 = lane & 15, g = lane >> 4;
  int n0 = blockIdx.x * 32;
  int j = w*16 + l15;

  // ---- stage 1: root transform ----
  f32x4 acc1[2];
  #pragma unroll
  for (int rt = 0; rt < 2; ++rt){ acc1[rt][0]=0.f; acc1[rt][1]=0.f; acc1[rt][2]=0.f; acc1[rt][3]=0.f; }
  bf16x8 ah[2][2];
  #pragma unroll
  for (int ks = 0; ks < 2; ++ks){
    bf16x8 b = *reinterpret_cast<const bf16x8*>(rootT + (size_t)j*64 + g*8 + ks*32);
    #pragma unroll
    for (int rt = 0; rt < 2; ++rt){
      bf16x8 a = *reinterpret_cast<const bf16x8*>(outbf + (size_t)(n0 + rt*16 + l15)*64 + g*8 + ks*32);
      acc1[rt] = __builtin_amdgcn_mfma_f32_16x16x32_bf16(a, b, acc1[rt], 0, 0, 0);
      ah[rt][ks] = *reinterpret_cast<const bf16x8*>(hbf + (size_t)(n0 + rt*16 + l15)*64 + g*8 + ks*32);
    }
  }
  {
    float cb = conv_b[j];
    #pragma unroll
    for (int rt = 0; rt < 2; ++rt){
      #pragma unroll
      for (int r = 0; r < 4; ++r){
        int row = rt*16 + g*4 + r;
        int node = n0 + row;
        float inv = 1.0f/fmaxf(deg[node], 1.0f);
        float mval = fmaxf(acc1[rt][r] + agg[(size_t)node*64 + j]*inv + cb, 0.0f);
        agg[(size_t)node*64 + j] = 0.0f;
        int gran = (j >> 3) ^ (row & 7);
        mbf[row*64 + (gran<<3) + (j & 7)] = f2bfu(mval);
      }
    }
  }
  __syncthreads();   // mbf visible; outbf/hbf reads drained

  // ---- stage 2: gates ----
  f32x4 gx[3][2], gh[3][2];
  #pragma unroll
  for (int ci = 0; ci < 3; ++ci){
    #pragma unroll
    for (int rt = 0; rt < 2; ++rt){
      gx[ci][rt][0]=0.f; gx[ci][rt][1]=0.f; gx[ci][rt][2]=0.f; gx[ci][rt][3]=0.f;
      gh[ci][rt][0]=0.f; gh[ci][rt][1]=0.f; gh[ci][rt][2]=0.f; gh[ci][rt][3]=0.f;
    }
  }
  #pragma unroll
  for (int ks = 0; ks < 2; ++ks){
    bf16x8 am[2];
    #pragma unroll
    for (int rt = 0; rt < 2; ++rt){
      int arow = rt*16 + l15;
      int agran = (g + ks*4) ^ (l15 & 7);
      am[rt] = *reinterpret_cast<const bf16x8*>(&mbf[arow*64 + (agran<<3)]);
    }
    #pragma unroll
    for (int ci = 0; ci < 3; ++ci){
      int c = (w + ci*4)*16 + l15;     // abs gate column (ci = gate)
      bf16x8 bx = *reinterpret_cast<const bf16x8*>(wih + (size_t)c*64 + g*8 + ks*32);
      bf16x8 bh = *reinterpret_cast<const bf16x8*>(whh + (size_t)c*64 + g*8 + ks*32);
      #pragma unroll
      for (int rt = 0; rt < 2; ++rt){
        gx[ci][rt] = __builtin_amdgcn_mfma_f32_16x16x32_bf16(am[rt], bx, gx[ci][rt], 0, 0, 0);
        gh[ci][rt] = __builtin_amdgcn_mfma_f32_16x16x32_bf16(ah[rt][ks], bh, gh[ci][rt], 0, 0, 0);
      }
    }
  }
  // ---- epilogue: GRU update, fully in-register ----
  float bxr = bih[j], bxz = bih[64+j], bxn = bih[128+j];
  float bhr = bhh[j], bhz = bhh[64+j], bhn = bhh[128+j];
  #pragma unroll
  for (int rt = 0; rt < 2; ++rt){
    #pragma unroll
    for (int r = 0; r < 4; ++r){
      int node = n0 + rt*16 + g*4 + r;
      float gxr = gx[0][rt][r] + bxr, gxz = gx[1][rt][r] + bxz, gxn = gx[2][rt][r] + bxn;
      float ghr = gh[0][rt][r] + bhr, ghz = gh[1][rt][r] + bhz, ghn = gh[2][rt][r] + bhn;
      float rr = sigm(gxr + ghr), zz = sigm(gxz + ghz);
      float nn_ = tanhf(gxn + rr*ghn);
      float hold = h[(size_t)node*64 + j];
      float hn = (1.0f - zz)*nn_ + zz*hold;
      h[(size_t)node*64 + j]   = hn;
      out[(size_t)node*64 + j] = hn;
      ushortT u = f2bfu(hn);
      outbf[(size_t)node*64 + j] = u;
      hbf[(size_t)node*64 + j]   = u;
    }
  }
}

// ------------- Set2Set: fused LSTM cell + attention, 7-slot state pipeline -------------
__global__ void k_s2s2(const float* __restrict__ out, const float* __restrict__ wi,
                       const float* __restrict__ wh, const float* __restrict__ bi,
                       const float* __restrict__ bh, float* __restrict__ st, int it){
  const float* sr = st + it*256;
  float* sw = st + (it+1)*256;
  __shared__ float qs[128], hsl[64], gg[256];
  __shared__ float ob[128*65], wl[128], zred[128], part[256];
  int tid = threadIdx.x;      // 256
  int n0 = blockIdx.x * 128;

  // ---- cell (computed redundantly by every block) ----
  if (tid < 64) qs[tid] = sr[tid];
  else if (tid < 128){
    float Z = sr[192];
    qs[tid] = (Z != 0.0f) ? sr[128 + (tid-64)]/Z : 0.0f;
  }
  __syncthreads();
  {
    float a = bi[tid] + bh[tid];
    #pragma unroll 8
    for (int k = 0; k < 128; ++k) a += qs[k]*wi[tid*128 + k];
    #pragma unroll 8
    for (int k = 0; k < 64;  ++k) a += sr[k]*wh[tid*64 + k];
    gg[tid] = a;
  }
  __syncthreads();
  if (tid < 64){
    float iv = sigm(gg[tid]), fv = sigm(gg[64+tid]);
    float gv = tanhf(gg[128+tid]), ov = sigm(gg[192+tid]);
    float c = fv*sr[64+tid] + iv*gv;
    float hnew = ov*tanhf(c);
    hsl[tid] = hnew;
    if (blockIdx.x == 0){ sw[64+tid] = c; sw[tid] = hnew; }
  }
  // ---- attention over this block's 128 nodes ----
  #pragma unroll
  for (int rr = 0; rr < 8; ++rr){
    int idx = rr*1024 + tid*4;
    int nl = idx >> 6, jj = idx & 63;
    float4 v = make_float4(0.f,0.f,0.f,0.f);
    if (n0 + nl < NN) v = *reinterpret_cast<const float4*>(&out[(size_t)(n0+nl)*64 + jj]);
    ob[nl*65 + jj + 0] = v.x; ob[nl*65 + jj + 1] = v.y;
    ob[nl*65 + jj + 2] = v.z; ob[nl*65 + jj + 3] = v.w;
  }
  __syncthreads();
  if (tid < 128){
    float e = 0.f;
    #pragma unroll 8
    for (int jj = 0; jj < 64; ++jj) e += ob[tid*65 + jj]*hsl[jj];
    float wv = (n0 + tid < NN) ? expf(e) : 0.f;
    wl[tid] = wv; zred[tid] = wv;
  }
  __syncthreads();
  if (tid < 64) zred[tid] += zred[tid + 64];
  __syncthreads();
  if (tid < 32) zred[tid] += zred[tid + 32];
  __syncthreads();
  if (tid < 16) zred[tid] += zred[tid + 16];
  __syncthreads();
  if (tid < 8) zred[tid] += zred[tid + 8];
  __syncthreads();
  if (tid == 0){
    float z = zred[0]+zred[1]+zred[2]+zred[3]+zred[4]+zred[5]+zred[6]+zred[7];
    atomicAdd(&sw[192], z);
  }
  {
    int gq = tid >> 6, d = tid & 63;
    float acc = 0.f;
    #pragma unroll 8
    for (int i = 0; i < 32; ++i){
      int nl = gq*32 + i;
      acc += wl[nl]*ob[nl*65 + d];
    }
    part[tid] = acc;
  }
  __syncthreads();
  if (tid < 64)
    atomicAdd(&sw[128 + tid], part[tid] + part[64+tid] + part[128+tid] + part[192+tid]);
}

// ------------- head -------------
__global__ void k_z(const float* __restrict__ out, const float* __restrict__ st,
                    const int* __restrict__ nonring, ushortT* __restrict__ zbf){
  const float* s6 = st + 6*256;
  int idx = blockIdx.x*256 + threadIdx.x;         // T*384 exact
  int t = idx / 384, c = idx % 384;
  float v;
  if (c < 256){
    int a = c*16 + (t >> 6);
    int node = nonring[a];
    v = out[(size_t)node*64 + (t & 63)];
  } else {
    int pi = t >> 3;                              // pool index (quirky repeat)
    v = (pi < 64) ? s6[pi] : s6[128 + (pi - 64)] / s6[192];
  }
  zbf[idx] = f2bfu(v);
}

// memory LSTM via MFMA: gates = zbf @ wmem^T (+biases); hm = sig(o)*tanh(sig(i)*tanh(g))
__global__ __launch_bounds__(256) void k_mem2(
    const ushortT* __restrict__ zbf, const ushortT* __restrict__ wmem,
    const float* __restrict__ membi, const float* __restrict__ membh,
    ushortT* __restrict__ hmbf){
  int tid = threadIdx.x;
  int w = tid >> 6, lane = tid & 63;
  int l15 = lane & 15, g = lane >> 4;
  int m0 = blockIdx.x * 32;
  int jw = blockIdx.y * 64 + w * 16;

  f32x4 ai[2], ag[2], ao[2];
  #pragma unroll
  for (int m = 0; m < 2; ++m){
    #pragma unroll
    for (int r = 0; r < 4; ++r){ ai[m][r]=0.f; ag[m][r]=0.f; ao[m][r]=0.f; }
  }
  const ushortT* a0p = zbf + (size_t)(m0 + l15)*384 + g*8;
  const ushortT* a1p = zbf + (size_t)(m0 + 16 + l15)*384 + g*8;
  const ushortT* bip = wmem + (size_t)(jw + l15)*384 + g*8;
  const ushortT* bgp = wmem + (size_t)(768 + jw + l15)*384 + g*8;
  const ushortT* bop = wmem + (size_t)(1152 + jw + l15)*384 + g*8;
  #pragma unroll
  for (int ks = 0; ks < 12; ++ks){
    bf16x8 a0 = *reinterpret_cast<const bf16x8*>(a0p + ks*32);
    bf16x8 a1 = *reinterpret_cast<const bf16x8*>(a1p + ks*32);
    bf16x8 bi = *reinterpret_cast<const bf16x8*>(bip + ks*32);
    bf16x8 bg = *reinterpret_cast<const bf16x8*>(bgp + ks*32);
    bf16x8 bo = *reinterpret_cast<const bf16x8*>(bop + ks*32);
    ai[0] = __builtin_amdgcn_mfma_f32_16x16x32_bf16(a0, bi, ai[0], 0, 0, 0);
    ai[1] = __builtin_amdgcn_mfma_f32_16x16x32_bf16(a1, bi, ai[1], 0, 0, 0);
    ag[0] = __builtin_amdgcn_mfma_f32_16x16x32_bf16(a0, bg, ag[0], 0, 0, 0);
    ag[1] = __builtin_amdgcn_mfma_f32_16x16x32_bf16(a1, bg, ag[1], 0, 0, 0);
    ao[0] = __builtin_amdgcn_mfma_f32_16x16x32_bf16(a0, bo, ao[0], 0, 0, 0);
    ao[1] = __builtin_amdgcn_mfma_f32_16x16x32_bf16(a1, bo, ao[1], 0, 0, 0);
  }
  int j = jw + l15;
  float bI = membi[j]        + membh[j];
  float bG = membi[768 + j]  + membh[768 + j];
  float bO = membi[1152 + j] + membh[1152 + j];
  #pragma unroll
  for (int m = 0; m < 2; ++m){
    #pragma unroll
    for (int r = 0; r < 4; ++r){
      int t = m0 + m*16 + g*4 + r;
      float gi = ai[m][r] + bI;
      float gG = ag[m][r] + bG;
      float go = ao[m][r] + bO;
      float cm = sigm(gi)*tanhf(gG);
      hmbf[(size_t)t*384 + j] = f2bfu(sigm(go)*tanhf(cm));
    }
  }
}

// fin stage 1 via MFMA: hid = relu(hm @ W1^T + b1)  [1024 x 128] f32
__global__ __launch_bounds__(256) void k_fin1(
    const ushortT* __restrict__ hmbf, const ushortT* __restrict__ w1bf,
    const float* __restrict__ b1, float* __restrict__ hid){
  int tid = threadIdx.x;
  int w = tid >> 6, lane = tid & 63;
  int l15 = lane & 15, g = lane >> 4;
  int m0 = blockIdx.x * 32;
  int cw = blockIdx.y * 64 + w * 16;

  f32x4 acc[2];
  #pragma unroll
  for (int m = 0; m < 2; ++m){
    #pragma unroll
    for (int r = 0; r < 4; ++r) acc[m][r] = 0.f;
  }
  const ushortT* a0p = hmbf + (size_t)(m0 + l15)*384 + g*8;
  const ushortT* a1p = hmbf + (size_t)(m0 + 16 + l15)*384 + g*8;
  const ushortT* bp  = w1bf + (size_t)(cw + l15)*384 + g*8;
  #pragma unroll
  for (int ks = 0; ks < 12; ++ks){
    bf16x8 a0 = *reinterpret_cast<const bf16x8*>(a0p + ks*32);
    bf16x8 a1 = *reinterpret_cast<const bf16x8*>(a1p + ks*32);
    bf16x8 b  = *reinterpret_cast<const bf16x8*>(bp + ks*32);
    acc[0] = __builtin_amdgcn_mfma_f32_16x16x32_bf16(a0, b, acc[0], 0, 0, 0);
    acc[1] = __builtin_amdgcn_mfma_f32_16x16x32_bf16(a1, b, acc[1], 0, 0, 0);
  }
  int c = cw + l15;
  float bv = b1[c];
  #pragma unroll
  for (int m = 0; m < 2; ++m){
    #pragma unroll
    for (int r = 0; r < 4; ++r){
      int t = m0 + m*16 + g*4 + r;
      hid[(size_t)t*128 + c] = fmaxf(acc[m][r] + bv, 0.0f);
    }
  }
}

// fin stage 2: y[t][j] = b2[j] + hid[t] . W2[j]   (j < 6)
__global__ void k_fin2(const float* __restrict__ hid, const float* __restrict__ W2,
                       const float* __restrict__ b2, float* __restrict__ y){
  int tid = threadIdx.x;                 // 256
  int t = blockIdx.x*32 + (tid >> 3);    // grid 32 exact
  int j = tid & 7;
  if (j >= 6) return;
  float a = b2[j];
  const float* hp = hid + (size_t)t*128;
  const float* wp = W2 + j*128;
  #pragma unroll 8
  for (int k = 0; k < 128; ++k) a += hp[k]*wp[k];
  y[t*6 + j] = a;
}

extern "C" void kernel_launch(void* const* d_in, const int* in_sizes, int n_in,
                              void* d_out, int out_size, void* d_ws, size_t ws_size,
                              hipStream_t stream){
  const float* x      = (const float*)d_in[0];
  const float* ea     = (const float*)d_in[1];
  const float* W0     = (const float*)d_in[2];
  const float* b0     = (const float*)d_in[3];
  const float* We1    = (const float*)d_in[4];
  const float* be1    = (const float*)d_in[5];
  const float* We2    = (const float*)d_in[6];
  const float* be2    = (const float*)d_in[7];
  const float* root   = (const float*)d_in[8];
  const float* conv_b = (const float*)d_in[9];
  const float* gwih   = (const float*)d_in[10];
  const float* gwhh   = (const float*)d_in[11];
  const float* gbih   = (const float*)d_in[12];
  const float* gbhh   = (const float*)d_in[13];
  const float* s2swi  = (const float*)d_in[14];
  const float* s2swh  = (const float*)d_in[15];
  const float* s2sbi  = (const float*)d_in[16];
  const float* s2sbh  = (const float*)d_in[17];
  const float* memwi  = (const float*)d_in[18];
  const float* membi  = (const float*)d_in[20];
  const float* membh  = (const float*)d_in[21];
  const float* W1     = (const float*)d_in[22];
  const float* b1     = (const float*)d_in[23];
  const float* W2     = (const float*)d_in[24];
  const float* b2     = (const float*)d_in[25];
  const int*   eidx   = (const int*)d_in[26];
  const int*   nonr   = (const int*)d_in[27];
  const int* src = eidx, *dst = eidx + NE;
  float* y = (float*)d_out;

  char* wsb = (char*)d_ws;
  size_t off = 0;
  auto alloc = [&](size_t bytes){ size_t o = off; off += (bytes + 255) & ~(size_t)255; return o; };
  float* out    = (float*)(wsb + alloc((size_t)NN*64*4));
  float* h      = (float*)(wsb + alloc((size_t)NN*64*4));
  float* agg    = (float*)(wsb + alloc((size_t)NN*64*4));
  float* deg    = (float*)(wsb + alloc((size_t)NN*4));
  float* st     = (float*)(wsb + alloc(7*256*4));
  float* hid    = (float*)(wsb + alloc((size_t)NT*128*4));
  ushortT* Rbf  = (ushortT*)(wsb + alloc((size_t)NE*128*2));
  ushortT* We2bf= (ushortT*)(wsb + alloc((size_t)4096*128*2));
  ushortT* wmem = (ushortT*)(wsb + alloc((size_t)1536*384*2));
  ushortT* w1bf = (ushortT*)(wsb + alloc((size_t)128*384*2));
  ushortT* zbf  = (ushortT*)(wsb + alloc((size_t)NT*384*2));
  ushortT* hmbf = (ushortT*)(wsb + alloc((size_t)NT*384*2));
  ushortT* outbf= (ushortT*)(wsb + alloc((size_t)NN*64*2));
  ushortT* hbf  = (ushortT*)(wsb + alloc((size_t)NN*64*2));
  ushortT* gwihbf = (ushortT*)(wsb + alloc((size_t)192*64*2));
  ushortT* gwhhbf = (ushortT*)(wsb + alloc((size_t)192*64*2));
  ushortT* rootTbf= (ushortT*)(wsb + alloc((size_t)64*64*2));
  (void)ws_size; (void)n_in; (void)in_sizes; (void)out_size;

  hipMemsetAsync(deg, 0, (size_t)NN*4, stream);
  hipMemsetAsync(st, 0, 7*256*4, stream);
  hipMemsetAsync(agg, 0, (size_t)NN*64*4, stream);
  k_lin0<<<NN*64/256, 256, 0, stream>>>(x, W0, b0, out, h, outbf, hbf);
  k_deg<<<(NE+255)/256, 256, 0, stream>>>(dst, deg);
  k_edgemlp<<<NE*128/256, 256, 0, stream>>>(ea, We1, be1, Rbf);
  k_prep<<<(PREP_T+255)/256, 256, 0, stream>>>(We2, memwi, W1, gwih, gwhh, root,
                                               We2bf, wmem, w1bf, gwihbf, gwhhbf, rootTbf);

  for (int it = 0; it < 6; ++it){
    k_fmsg<<<(NE + EB - 1)/EB, 256, 0, stream>>>(Rbf, We2bf, be2, outbf, src, dst, agg);
    k_gru2<<<NN/32, 256, 0, stream>>>(agg, deg, rootTbf, conv_b, gwihbf, gwhhbf,
                                      gbih, gbhh, out, h, outbf, hbf);
  }

  for (int it = 0; it < 6; ++it){
    k_s2s2<<<(NN + 127)/128, 256, 0, stream>>>(out, s2swi, s2swh, s2sbi, s2sbh, st, it);
  }

  k_z<<<NT*384/256, 256, 0, stream>>>(out, st, nonr, zbf);
  k_mem2<<<dim3(32, 6), 256, 0, stream>>>(zbf, wmem, membi, membh, hmbf);
  k_fin1<<<dim3(32, 2), 256, 0, stream>>>(hmbf, w1bf, b1, hid);
  k_fin2<<<32, 256, 0, stream>>>(hid, W2, b2, y);
}

// Round 15
// 644.165 us; speedup vs baseline: 1.6772x; 1.0399x over previous
//
#include <hip/hip_runtime.h>
#include <hip/hip_bf16.h>

#define NN 20000
#define NE 60000
#define NT 1024

typedef unsigned short ushortT;
typedef __attribute__((ext_vector_type(8))) short bf16x8;
typedef __attribute__((ext_vector_type(8))) unsigned short u16x8;
typedef __attribute__((ext_vector_type(4))) float f32x4;

__device__ __forceinline__ float sigm(float x){ return 1.0f/(1.0f+expf(-x)); }
__device__ __forceinline__ float bfu2f(ushortT u){ return __uint_as_float(((unsigned)u)<<16); }
__device__ __forceinline__ ushortT f2bfu(float f){
  __hip_bfloat16 b = __float2bfloat16(f);
  return *reinterpret_cast<ushortT*>(&b);
}

// ---------------- lin0: outbf = bf16(relu(x @ W0.T + b0)) ----------------
__global__ void k_lin0(const float* __restrict__ x, const float* __restrict__ W0,
                       const float* __restrict__ b0, ushortT* __restrict__ outbf){
  int idx = blockIdx.x*256 + threadIdx.x;       // N*64 exact
  int n = idx >> 6, j = idx & 63;
  float a = b0[j] + x[n*3+0]*W0[j*3+0] + x[n*3+1]*W0[j*3+1] + x[n*3+2]*W0[j*3+2];
  outbf[idx] = f2bfu(fmaxf(a, 0.0f));
}

__global__ void k_deg(const int* __restrict__ dst, float* __restrict__ deg){
  int e = blockIdx.x*256 + threadIdx.x;
  if (e < NE) atomicAdd(&deg[dst[e]], 1.0f);
}

// ------------- edge MLP hidden: R = relu(edge_attr @ We1.T + be1) (bf16) ----
__global__ void k_edgemlp(const float* __restrict__ ea, const float* __restrict__ We1,
                          const float* __restrict__ be1, ushortT* __restrict__ Rbf){
  int idx = blockIdx.x*256 + threadIdx.x;       // E*128 exact
  int e = idx >> 7, k = idx & 127;
  float a = be1[k];
  #pragma unroll
  for (int j = 0; j < 7; ++j) a += ea[e*7+j]*We1[k*7+j];
  Rbf[idx] = f2bfu(fmaxf(a, 0.0f));
}

// ------------- fused weight prep: bf16 cvts + rootT transpose -------------
#define PREP_T ((4096*128) + (1536*384) + (128*384) + (192*64) + (192*64) + (64*64))
__global__ void k_prep(const float* __restrict__ We2, const float* __restrict__ memwi,
                       const float* __restrict__ W1, const float* __restrict__ gwih,
                       const float* __restrict__ gwhh, const float* __restrict__ root,
                       ushortT* __restrict__ We2bf, ushortT* __restrict__ wmem,
                       ushortT* __restrict__ w1bf, ushortT* __restrict__ gwihbf,
                       ushortT* __restrict__ gwhhbf, ushortT* __restrict__ rootTbf){
  int idx = blockIdx.x*256 + threadIdx.x;
  if (idx < 4096*128){ We2bf[idx] = f2bfu(We2[idx]); return; }
  idx -= 4096*128;
  if (idx < 1536*384){ wmem[idx] = f2bfu(memwi[idx]); return; }
  idx -= 1536*384;
  if (idx < 128*384){ w1bf[idx] = f2bfu(W1[idx]); return; }
  idx -= 128*384;
  if (idx < 192*64){ gwihbf[idx] = f2bfu(gwih[idx]); return; }
  idx -= 192*64;
  if (idx < 192*64){ gwhhbf[idx] = f2bfu(gwhh[idx]); return; }
  idx -= 192*64;
  if (idx < 64*64){ int d = idx >> 6, j = idx & 63; rootTbf[j*64 + d] = f2bfu(root[idx]); }
}

// ---------- fused NNConv message: agg[dst[e]] += out[src[e]] @ (R[e]@We2^T + be2) ----------
// R14-proven wave-autonomous structure: wave w owns f-cols [w*16,w*16+16), stages
// its own 16x128 B-tile into private LDS (2-deep), zero in-loop barriers, counted
// wave-local vmcnt. LDS ~66KB -> 2 blocks/CU.
#define EB 128
__global__ __launch_bounds__(256, 2) void k_fmsg(
    const ushortT* __restrict__ Rbf, const ushortT* __restrict__ We2bf,
    const float* __restrict__ be2, const ushortT* __restrict__ outbf,
    const int* __restrict__ src, const int* __restrict__ dst,
    float* __restrict__ agg)
{
  __shared__ ushortT o_sT[64][136];      // bf16 out[src[e]] transposed [d][edge]
  __shared__ ushortT bufB[4][2][2048];   // per-wave [w][buf][16 rows x 128 k]
  __shared__ float   be2q[64][64];       // be2 reshaped [d][f]
  __shared__ int     dst_s[EB];

  int tid = threadIdx.x;
  int e0 = blockIdx.x * EB;
  int w = tid >> 6, lane = tid & 63;
  int l15 = lane & 15, g = lane >> 4;    // g in 0..3
  int f = (w << 4) + l15;                // this lane's f column

  auto stage = [&](int d, int b){
    #pragma unroll
    for (int i = 0; i < 4; ++i){
      int s = i*64 + lane;               // 0..255
      int row = s >> 4, kslot = s & 15;  // row 0..15 (f-col within wave tile)
      const ushortT* gp = We2bf + (size_t)((d<<6) + (w<<4) + row)*128 + ((kslot ^ (row & 7))<<3);
      __builtin_amdgcn_global_load_lds(
          (const __attribute__((address_space(1))) void*)gp,
          (__attribute__((address_space(3))) void*)&bufB[w][b][(size_t)i*512], 16, 0, 0);
    }
  };
  stage(0, 0);   // tile 0 into private buf 0

  // ---- prologue: dst + o gather (bf16, transposed; 2 threads/edge), be2 copy ----
  {
    int ei = tid >> 1;
    int ge = e0 + ei;
    int sn = (ge < NE) ? src[ge] : 0;
    if (tid < EB) dst_s[tid] = (e0 + tid < NE) ? dst[e0 + tid] : -1;
    int half = (tid & 1) * 32;
    const ushortT* op = outbf + (size_t)sn*64 + half;
    #pragma unroll
    for (int i = 0; i < 4; ++i){
      u16x8 v = *reinterpret_cast<const u16x8*>(op + i*8);
      #pragma unroll
      for (int j = 0; j < 8; ++j) o_sT[half + i*8 + j][ei] = v[j];
    }
  }
  #pragma unroll
  for (int i = 0; i < 4; ++i){
    int idx = tid*16 + i*4;                       // 4096 floats total
    *reinterpret_cast<float4*>(&be2q[0][0] + idx) =
        *reinterpret_cast<const float4*>(be2 + idx);
  }

  // A fragments: R rows for this block's 128 edges, all K=128 (4 k-steps)
  bf16x8 af[8][4];
  #pragma unroll
  for (int t = 0; t < 8; ++t){
    #pragma unroll
    for (int ks = 0; ks < 4; ++ks){
      int ge = e0 + t*16 + l15;
      bf16x8 z = {0,0,0,0,0,0,0,0};
      af[t][ks] = (ge < NE) ? *reinterpret_cast<const bf16x8*>(Rbf + (size_t)ge*128 + ks*32 + g*8) : z;
    }
  }

  f32x4 msg[8];
  #pragma unroll
  for (int t = 0; t < 8; ++t){ msg[t][0]=0.f; msg[t][1]=0.f; msg[t][2]=0.f; msg[t][3]=0.f; }
  __syncthreads();   // o_sT / be2q / dst_s visible (only barrier in the kernel)

  for (int d = 0; d < 64; ++d){
    if (d < 63) stage(d + 1, (d + 1) & 1);
    if (d < 63){
      asm volatile("s_waitcnt vmcnt(4)" ::: "memory");   // own stage(d) complete
    } else {
      asm volatile("s_waitcnt vmcnt(0)" ::: "memory");
    }
    __builtin_amdgcn_sched_barrier(0);
    int b = d & 1;
    bf16x8 bf[4];
    #pragma unroll
    for (int ks = 0; ks < 4; ++ks)
      bf[ks] = *reinterpret_cast<const bf16x8*>(&bufB[w][b][ l15*128 + ((((ks<<2)+g) ^ (l15&7))<<3) ]);
    f32x4 ac[8];
    #pragma unroll
    for (int t = 0; t < 8; ++t){ ac[t][0]=0.f; ac[t][1]=0.f; ac[t][2]=0.f; ac[t][3]=0.f; }
    __builtin_amdgcn_s_setprio(1);
    #pragma unroll
    for (int ks = 0; ks < 4; ++ks){
      #pragma unroll
      for (int t = 0; t < 8; ++t)
        ac[t] = __builtin_amdgcn_mfma_f32_16x16x32_bf16(af[t][ks], bf[ks], ac[t], 0, 0, 0);
    }
    __builtin_amdgcn_s_setprio(0);
    float be2v = be2q[d][f];
    #pragma unroll
    for (int t = 0; t < 8; ++t){
      ushort4 ou = *reinterpret_cast<const ushort4*>(&o_sT[d][t*16 + g*4]);
      msg[t][0] += bfu2f(ou.x)*(ac[t][0] + be2v);
      msg[t][1] += bfu2f(ou.y)*(ac[t][1] + be2v);
      msg[t][2] += bfu2f(ou.z)*(ac[t][2] + be2v);
      msg[t][3] += bfu2f(ou.w)*(ac[t][3] + be2v);
    }
  }

  #pragma unroll
  for (int t = 0; t < 8; ++t){
    #pragma unroll
    for (int r = 0; r < 4; ++r){
      int el = t*16 + g*4 + r;
      int tn = dst_s[el];
      if (tn >= 0) atomicAdd(&agg[(size_t)tn*64 + f], msg[t][r]);
    }
  }
}

// ------------- NNConv epilogue + GRU cell via MFMA (32 nodes/block, grid 625) -------------
// Single bf16 state array outbf (out == h in the reference after every step).
__global__ __launch_bounds__(256) void k_gru2(
    const float* __restrict__ agg_in, const float* __restrict__ deg,
    const ushortT* __restrict__ rootT, const float* __restrict__ conv_b,
    const ushortT* __restrict__ wih, const ushortT* __restrict__ whh,
    const float* __restrict__ bih, const float* __restrict__ bhh,
    ushortT* __restrict__ outbf)
{
  __shared__ ushortT mbf[32*64];
  float* agg = const_cast<float*>(agg_in);
  int tid = threadIdx.x;
  int w = tid >> 6, lane = tid & 63;
  int l15 = lane & 15, g = lane >> 4;
  int n0 = blockIdx.x * 32;
  int j = w*16 + l15;

  // ---- stage 1: root transform ----
  f32x4 acc1[2];
  #pragma unroll
  for (int rt = 0; rt < 2; ++rt){ acc1[rt][0]=0.f; acc1[rt][1]=0.f; acc1[rt][2]=0.f; acc1[rt][3]=0.f; }
  bf16x8 ah[2][2];
  #pragma unroll
  for (int ks = 0; ks < 2; ++ks){
    bf16x8 b = *reinterpret_cast<const bf16x8*>(rootT + (size_t)j*64 + g*8 + ks*32);
    #pragma unroll
    for (int rt = 0; rt < 2; ++rt){
      bf16x8 a = *reinterpret_cast<const bf16x8*>(outbf + (size_t)(n0 + rt*16 + l15)*64 + g*8 + ks*32);
      acc1[rt] = __builtin_amdgcn_mfma_f32_16x16x32_bf16(a, b, acc1[rt], 0, 0, 0);
      ah[rt][ks] = a;      // h == out (same bf16 state)
    }
  }
  {
    float cb = conv_b[j];
    #pragma unroll
    for (int rt = 0; rt < 2; ++rt){
      #pragma unroll
      for (int r = 0; r < 4; ++r){
        int row = rt*16 + g*4 + r;
        int node = n0 + row;
        float inv = 1.0f/fmaxf(deg[node], 1.0f);
        float mval = fmaxf(acc1[rt][r] + agg[(size_t)node*64 + j]*inv + cb, 0.0f);
        agg[(size_t)node*64 + j] = 0.0f;
        int gran = (j >> 3) ^ (row & 7);
        mbf[row*64 + (gran<<3) + (j & 7)] = f2bfu(mval);
      }
    }
  }
  __syncthreads();   // mbf visible; outbf reads drained

  // ---- stage 2: gates ----
  f32x4 gx[3][2], gh[3][2];
  #pragma unroll
  for (int ci = 0; ci < 3; ++ci){
    #pragma unroll
    for (int rt = 0; rt < 2; ++rt){
      gx[ci][rt][0]=0.f; gx[ci][rt][1]=0.f; gx[ci][rt][2]=0.f; gx[ci][rt][3]=0.f;
      gh[ci][rt][0]=0.f; gh[ci][rt][1]=0.f; gh[ci][rt][2]=0.f; gh[ci][rt][3]=0.f;
    }
  }
  #pragma unroll
  for (int ks = 0; ks < 2; ++ks){
    bf16x8 am[2];
    #pragma unroll
    for (int rt = 0; rt < 2; ++rt){
      int arow = rt*16 + l15;
      int agran = (g + ks*4) ^ (l15 & 7);
      am[rt] = *reinterpret_cast<const bf16x8*>(&mbf[arow*64 + (agran<<3)]);
    }
    #pragma unroll
    for (int ci = 0; ci < 3; ++ci){
      int c = (w + ci*4)*16 + l15;     // abs gate column (ci = gate)
      bf16x8 bx = *reinterpret_cast<const bf16x8*>(wih + (size_t)c*64 + g*8 + ks*32);
      bf16x8 bh = *reinterpret_cast<const bf16x8*>(whh + (size_t)c*64 + g*8 + ks*32);
      #pragma unroll
      for (int rt = 0; rt < 2; ++rt){
        gx[ci][rt] = __builtin_amdgcn_mfma_f32_16x16x32_bf16(am[rt], bx, gx[ci][rt], 0, 0, 0);
        gh[ci][rt] = __builtin_amdgcn_mfma_f32_16x16x32_bf16(ah[rt][ks], bh, gh[ci][rt], 0, 0, 0);
      }
    }
  }
  // ---- epilogue: GRU update, fully in-register ----
  float bxr = bih[j], bxz = bih[64+j], bxn = bih[128+j];
  float bhr = bhh[j], bhz = bhh[64+j], bhn = bhh[128+j];
  #pragma unroll
  for (int rt = 0; rt < 2; ++rt){
    #pragma unroll
    for (int r = 0; r < 4; ++r){
      int node = n0 + rt*16 + g*4 + r;
      float gxr = gx[0][rt][r] + bxr, gxz = gx[1][rt][r] + bxz, gxn = gx[2][rt][r] + bxn;
      float ghr = gh[0][rt][r] + bhr, ghz = gh[1][rt][r] + bhz, ghn = gh[2][rt][r] + bhn;
      float rr = sigm(gxr + ghr), zz = sigm(gxz + ghz);
      float nn_ = tanhf(gxn + rr*ghn);
      float hold = bfu2f(outbf[(size_t)node*64 + j]);
      float hn = (1.0f - zz)*nn_ + zz*hold;
      outbf[(size_t)node*64 + j] = f2bfu(hn);
    }
  }
}

// ------------- Set2Set: fused LSTM cell + attention, 7-slot state pipeline -------------
__global__ void k_s2s2(const ushortT* __restrict__ outbf, const float* __restrict__ wi,
                       const float* __restrict__ wh, const float* __restrict__ bi,
                       const float* __restrict__ bh, float* __restrict__ st, int it){
  const float* sr = st + it*256;
  float* sw = st + (it+1)*256;
  __shared__ float qs[128], hsl[64], gg[256];
  __shared__ float ob[128*65], wl[128], zred[128], part[256];
  int tid = threadIdx.x;      // 256
  int n0 = blockIdx.x * 128;

  // ---- cell (computed redundantly by every block) ----
  if (tid < 64) qs[tid] = sr[tid];
  else if (tid < 128){
    float Z = sr[192];
    qs[tid] = (Z != 0.0f) ? sr[128 + (tid-64)]/Z : 0.0f;
  }
  __syncthreads();
  {
    float a = bi[tid] + bh[tid];
    #pragma unroll 8
    for (int k = 0; k < 128; ++k) a += qs[k]*wi[tid*128 + k];
    #pragma unroll 8
    for (int k = 0; k < 64;  ++k) a += sr[k]*wh[tid*64 + k];
    gg[tid] = a;
  }
  __syncthreads();
  if (tid < 64){
    float iv = sigm(gg[tid]), fv = sigm(gg[64+tid]);
    float gv = tanhf(gg[128+tid]), ov = sigm(gg[192+tid]);
    float c = fv*sr[64+tid] + iv*gv;
    float hnew = ov*tanhf(c);
    hsl[tid] = hnew;
    if (blockIdx.x == 0){ sw[64+tid] = c; sw[tid] = hnew; }
  }
  // ---- attention over this block's 128 nodes (bf16 source) ----
  #pragma unroll
  for (int rr = 0; rr < 4; ++rr){
    int idx = rr*2048 + tid*8;
    int nl = idx >> 6, jj = idx & 63;
    u16x8 v = {0,0,0,0,0,0,0,0};
    if (n0 + nl < NN) v = *reinterpret_cast<const u16x8*>(&outbf[(size_t)(n0+nl)*64 + jj]);
    #pragma unroll
    for (int j = 0; j < 8; ++j) ob[nl*65 + jj + j] = bfu2f(v[j]);
  }
  __syncthreads();
  if (tid < 128){
    float e = 0.f;
    #pragma unroll 8
    for (int jj = 0; jj < 64; ++jj) e += ob[tid*65 + jj]*hsl[jj];
    float wv = (n0 + tid < NN) ? expf(e) : 0.f;
    wl[tid] = wv; zred[tid] = wv;
  }
  __syncthreads();
  if (tid < 64) zred[tid] += zred[tid + 64];
  __syncthreads();
  if (tid < 32) zred[tid] += zred[tid + 32];
  __syncthreads();
  if (tid < 16) zred[tid] += zred[tid + 16];
  __syncthreads();
  if (tid < 8) zred[tid] += zred[tid + 8];
  __syncthreads();
  if (tid == 0){
    float z = zred[0]+zred[1]+zred[2]+zred[3]+zred[4]+zred[5]+zred[6]+zred[7];
    atomicAdd(&sw[192], z);
  }
  {
    int gq = tid >> 6, d = tid & 63;
    float acc = 0.f;
    #pragma unroll 8
    for (int i = 0; i < 32; ++i){
      int nl = gq*32 + i;
      acc += wl[nl]*ob[nl*65 + d];
    }
    part[tid] = acc;
  }
  __syncthreads();
  if (tid < 64)
    atomicAdd(&sw[128 + tid], part[tid] + part[64+tid] + part[128+tid] + part[192+tid]);
}

// ------------- head -------------
__global__ void k_z(const ushortT* __restrict__ outbf, const float* __restrict__ st,
                    const int* __restrict__ nonring, ushortT* __restrict__ zbf){
  const float* s6 = st + 6*256;
  int idx = blockIdx.x*256 + threadIdx.x;         // T*384 exact
  int t = idx / 384, c = idx % 384;
  if (c < 256){
    int a = c*16 + (t >> 6);
    int node = nonring[a];
    zbf[idx] = outbf[(size_t)node*64 + (t & 63)];
  } else {
    int pi = t >> 3;                              // pool index (quirky repeat)
    float v = (pi < 64) ? s6[pi] : s6[128 + (pi - 64)] / s6[192];
    zbf[idx] = f2bfu(v);
  }
}

// memory LSTM via MFMA: gates = zbf @ wmem^T (+biases); hm = sig(o)*tanh(sig(i)*tanh(g))
__global__ __launch_bounds__(256) void k_mem2(
    const ushortT* __restrict__ zbf, const ushortT* __restrict__ wmem,
    const float* __restrict__ membi, const float* __restrict__ membh,
    ushortT* __restrict__ hmbf){
  int tid = threadIdx.x;
  int w = tid >> 6, lane = tid & 63;
  int l15 = lane & 15, g = lane >> 4;
  int m0 = blockIdx.x * 32;
  int jw = blockIdx.y * 64 + w * 16;

  f32x4 ai[2], ag[2], ao[2];
  #pragma unroll
  for (int m = 0; m < 2; ++m){
    #pragma unroll
    for (int r = 0; r < 4; ++r){ ai[m][r]=0.f; ag[m][r]=0.f; ao[m][r]=0.f; }
  }
  const ushortT* a0p = zbf + (size_t)(m0 + l15)*384 + g*8;
  const ushortT* a1p = zbf + (size_t)(m0 + 16 + l15)*384 + g*8;
  const ushortT* bip = wmem + (size_t)(jw + l15)*384 + g*8;
  const ushortT* bgp = wmem + (size_t)(768 + jw + l15)*384 + g*8;
  const ushortT* bop = wmem + (size_t)(1152 + jw + l15)*384 + g*8;
  #pragma unroll
  for (int ks = 0; ks < 12; ++ks){
    bf16x8 a0 = *reinterpret_cast<const bf16x8*>(a0p + ks*32);
    bf16x8 a1 = *reinterpret_cast<const bf16x8*>(a1p + ks*32);
    bf16x8 bi = *reinterpret_cast<const bf16x8*>(bip + ks*32);
    bf16x8 bg = *reinterpret_cast<const bf16x8*>(bgp + ks*32);
    bf16x8 bo = *reinterpret_cast<const bf16x8*>(bop + ks*32);
    ai[0] = __builtin_amdgcn_mfma_f32_16x16x32_bf16(a0, bi, ai[0], 0, 0, 0);
    ai[1] = __builtin_amdgcn_mfma_f32_16x16x32_bf16(a1, bi, ai[1], 0, 0, 0);
    ag[0] = __builtin_amdgcn_mfma_f32_16x16x32_bf16(a0, bg, ag[0], 0, 0, 0);
    ag[1] = __builtin_amdgcn_mfma_f32_16x16x32_bf16(a1, bg, ag[1], 0, 0, 0);
    ao[0] = __builtin_amdgcn_mfma_f32_16x16x32_bf16(a0, bo, ao[0], 0, 0, 0);
    ao[1] = __builtin_amdgcn_mfma_f32_16x16x32_bf16(a1, bo, ao[1], 0, 0, 0);
  }
  int j = jw + l15;
  float bI = membi[j]        + membh[j];
  float bG = membi[768 + j]  + membh[768 + j];
  float bO = membi[1152 + j] + membh[1152 + j];
  #pragma unroll
  for (int m = 0; m < 2; ++m){
    #pragma unroll
    for (int r = 0; r < 4; ++r){
      int t = m0 + m*16 + g*4 + r;
      float gi = ai[m][r] + bI;
      float gG = ag[m][r] + bG;
      float go = ao[m][r] + bO;
      float cm = sigm(gi)*tanhf(gG);
      hmbf[(size_t)t*384 + j] = f2bfu(sigm(go)*tanhf(cm));
    }
  }
}

// fin stage 1 via MFMA: hid = relu(hm @ W1^T + b1)  [1024 x 128] f32
__global__ __launch_bounds__(256) void k_fin1(
    const ushortT* __restrict__ hmbf, const ushortT* __restrict__ w1bf,
    const float* __restrict__ b1, float* __restrict__ hid){
  int tid = threadIdx.x;
  int w = tid >> 6, lane = tid & 63;
  int l15 = lane & 15, g = lane >> 4;
  int m0 = blockIdx.x * 32;
  int cw = blockIdx.y * 64 + w * 16;

  f32x4 acc[2];
  #pragma unroll
  for (int m = 0; m < 2; ++m){
    #pragma unroll
    for (int r = 0; r < 4; ++r) acc[m][r] = 0.f;
  }
  const ushortT* a0p = hmbf + (size_t)(m0 + l15)*384 + g*8;
  const ushortT* a1p = hmbf + (size_t)(m0 + 16 + l15)*384 + g*8;
  const ushortT* bp  = w1bf + (size_t)(cw + l15)*384 + g*8;
  #pragma unroll
  for (int ks = 0; ks < 12; ++ks){
    bf16x8 a0 = *reinterpret_cast<const bf16x8*>(a0p + ks*32);
    bf16x8 a1 = *reinterpret_cast<const bf16x8*>(a1p + ks*32);
    bf16x8 b  = *reinterpret_cast<const bf16x8*>(bp + ks*32);
    acc[0] = __builtin_amdgcn_mfma_f32_16x16x32_bf16(a0, b, acc[0], 0, 0, 0);
    acc[1] = __builtin_amdgcn_mfma_f32_16x16x32_bf16(a1, b, acc[1], 0, 0, 0);
  }
  int c = cw + l15;
  float bv = b1[c];
  #pragma unroll
  for (int m = 0; m < 2; ++m){
    #pragma unroll
    for (int r = 0; r < 4; ++r){
      int t = m0 + m*16 + g*4 + r;
      hid[(size_t)t*128 + c] = fmaxf(acc[m][r] + bv, 0.0f);
    }
  }
}

// fin stage 2: y[t][j] = b2[j] + hid[t] . W2[j]   (j < 6)
__global__ void k_fin2(const float* __restrict__ hid, const float* __restrict__ W2,
                       const float* __restrict__ b2, float* __restrict__ y){
  int tid = threadIdx.x;                 // 256
  int t = blockIdx.x*32 + (tid >> 3);    // grid 32 exact
  int j = tid & 7;
  if (j >= 6) return;
  float a = b2[j];
  const float* hp = hid + (size_t)t*128;
  const float* wp = W2 + j*128;
  #pragma unroll 8
  for (int k = 0; k < 128; ++k) a += hp[k]*wp[k];
  y[t*6 + j] = a;
}

extern "C" void kernel_launch(void* const* d_in, const int* in_sizes, int n_in,
                              void* d_out, int out_size, void* d_ws, size_t ws_size,
                              hipStream_t stream){
  const float* x      = (const float*)d_in[0];
  const float* ea     = (const float*)d_in[1];
  const float* W0     = (const float*)d_in[2];
  const float* b0     = (const float*)d_in[3];
  const float* We1    = (const float*)d_in[4];
  const float* be1    = (const float*)d_in[5];
  const float* We2    = (const float*)d_in[6];
  const float* be2    = (const float*)d_in[7];
  const float* root   = (const float*)d_in[8];
  const float* conv_b = (const float*)d_in[9];
  const float* gwih   = (const float*)d_in[10];
  const float* gwhh   = (const float*)d_in[11];
  const float* gbih   = (const float*)d_in[12];
  const float* gbhh   = (const float*)d_in[13];
  const float* s2swi  = (const float*)d_in[14];
  const float* s2swh  = (const float*)d_in[15];
  const float* s2sbi  = (const float*)d_in[16];
  const float* s2sbh  = (const float*)d_in[17];
  const float* memwi  = (const float*)d_in[18];
  const float* membi  = (const float*)d_in[20];
  const float* membh  = (const float*)d_in[21];
  const float* W1     = (const float*)d_in[22];
  const float* b1     = (const float*)d_in[23];
  const float* W2     = (const float*)d_in[24];
  const float* b2     = (const float*)d_in[25];
  const int*   eidx   = (const int*)d_in[26];
  const int*   nonr   = (const int*)d_in[27];
  const int* src = eidx, *dst = eidx + NE;
  float* y = (float*)d_out;

  char* wsb = (char*)d_ws;
  size_t off = 0;
  auto alloc = [&](size_t bytes){ size_t o = off; off += (bytes + 255) & ~(size_t)255; return o; };
  float* agg    = (float*)(wsb + alloc((size_t)NN*64*4));
  float* deg    = (float*)(wsb + alloc((size_t)NN*4));
  float* st     = (float*)(wsb + alloc(7*256*4));
  float* hid    = (float*)(wsb + alloc((size_t)NT*128*4));
  ushortT* Rbf  = (ushortT*)(wsb + alloc((size_t)NE*128*2));
  ushortT* We2bf= (ushortT*)(wsb + alloc((size_t)4096*128*2));
  ushortT* wmem = (ushortT*)(wsb + alloc((size_t)1536*384*2));
  ushortT* w1bf = (ushortT*)(wsb + alloc((size_t)128*384*2));
  ushortT* zbf  = (ushortT*)(wsb + alloc((size_t)NT*384*2));
  ushortT* hmbf = (ushortT*)(wsb + alloc((size_t)NT*384*2));
  ushortT* outbf= (ushortT*)(wsb + alloc((size_t)NN*64*2));
  ushortT* gwihbf = (ushortT*)(wsb + alloc((size_t)192*64*2));
  ushortT* gwhhbf = (ushortT*)(wsb + alloc((size_t)192*64*2));
  ushortT* rootTbf= (ushortT*)(wsb + alloc((size_t)64*64*2));
  (void)ws_size; (void)n_in; (void)in_sizes; (void)out_size;

  hipMemsetAsync(deg, 0, (size_t)NN*4, stream);
  hipMemsetAsync(st, 0, 7*256*4, stream);
  hipMemsetAsync(agg, 0, (size_t)NN*64*4, stream);
  k_lin0<<<NN*64/256, 256, 0, stream>>>(x, W0, b0, outbf);
  k_deg<<<(NE+255)/256, 256, 0, stream>>>(dst, deg);
  k_edgemlp<<<NE*128/256, 256, 0, stream>>>(ea, We1, be1, Rbf);
  k_prep<<<(PREP_T+255)/256, 256, 0, stream>>>(We2, memwi, W1, gwih, gwhh, root,
                                               We2bf, wmem, w1bf, gwihbf, gwhhbf, rootTbf);

  for (int it = 0; it < 6; ++it){
    k_fmsg<<<(NE + EB - 1)/EB, 256, 0, stream>>>(Rbf, We2bf, be2, outbf, src, dst, agg);
    k_gru2<<<NN/32, 256, 0, stream>>>(agg, deg, rootTbf, conv_b, gwihbf, gwhhbf,
                                      gbih, gbhh, outbf);
  }

  for (int it = 0; it < 6; ++it){
    k_s2s2<<<(NN + 127)/128, 256, 0, stream>>>(outbf, s2swi, s2swh, s2sbi, s2sbh, st, it);
  }

  k_z<<<NT*384/256, 256, 0, stream>>>(outbf, st, nonr, zbf);
  k_mem2<<<dim3(32, 6), 256, 0, stream>>>(zbf, wmem, membi, membh, hmbf);
  k_fin1<<<dim3(32, 2), 256, 0, stream>>>(hmbf, w1bf, b1, hid);
  k_fin2<<<32, 256, 0, stream>>>(hid, W2, b2, y);
}